// Round 9
// baseline (185.333 us; speedup 1.0000x reference)
//
#include <hip/hip_runtime.h>
#include <hip/hip_fp16.h>

#define Bn   4
#define CINc 64
#define COUTc 64
#define Hn   128
#define Wn   128
#define HW   (Hn * Wn)
#define KKc  9
#define NOFF 18

typedef short bf16x8 __attribute__((ext_vector_type(8)));
typedef float f32x4  __attribute__((ext_vector_type(4)));
typedef float f32x2  __attribute__((ext_vector_type(2)));

__device__ inline unsigned short f2bf(float f) {   // RNE fp32 -> bf16
    unsigned int u = __float_as_uint(f);
    return (unsigned short)((u + 0x7fffu + ((u >> 16) & 1u)) >> 16);
}

__device__ inline void dma16(const void* g, void* l) {
#if __has_builtin(__builtin_amdgcn_global_load_lds)
    __builtin_amdgcn_global_load_lds(
        (__attribute__((address_space(1))) void*)(g),
        (__attribute__((address_space(3))) void*)(l), 16, 0, 0);
#else
    *(uint4*)l = *(const uint4*)g;
#endif
}

// ---------------------------------------------------------------------------
// prep_all (v11 layout) — unchanged.
// ---------------------------------------------------------------------------
__global__ __launch_bounds__(256) void prep_all(
        const float* __restrict__ x, unsigned short* __restrict__ xt,
        const float* __restrict__ w_off, const float* __restrict__ w_def,
        unsigned short* __restrict__ wkb_sw, unsigned short* __restrict__ wob_sw) {
    int gb = blockIdx.x;
    int t  = threadIdx.x;
    if (gb < 1024) {
        __shared__ float s[64][65];
        int half = gb & 1;
        int h    = (gb >> 1) & 127;
        int b    = gb >> 8;
        int w0   = half * 64;
        int w = t & 63, cg = t >> 6;

        const float* xb = x + (size_t)b * CINc * HW + (size_t)h * Wn + w0 + w;
        #pragma unroll
        for (int i = 0; i < 16; ++i) {
            int c = cg * 16 + i;
            s[c][w] = xb[(size_t)c * HW];
        }
        __syncthreads();

        int cpair = t & 31, pxg = t >> 5;
        unsigned* xtp = (unsigned*)xt;
        #pragma unroll
        for (int i = 0; i < 8; ++i) {
            int px = pxg * 8 + i;
            float v0 = s[cpair * 2][px], v1 = s[cpair * 2 + 1][px];
            unsigned d = (unsigned)f2bf(v0) | ((unsigned)f2bf(v1) << 16);
            xtp[(((size_t)(b * Hn + h) * Wn) + w0 + px) * 32 + cpair] = d;
        }
        return;
    }
    int idx = (gb - 1024) * 256 + t;
    if (idx < 36864) {
        int j = idx & 7, l = (idx >> 3) & 63, s = idx >> 9;
        int k = s >> 3, kc = (s >> 2) & 1, ot = s & 3;
        int l15 = l & 15, quad = l >> 4;
        int o = ot * 16 + l15, c = kc * 32 + quad * 8 + j;
        wkb_sw[idx] = f2bf(w_def[((size_t)o * 64 + c) * 9 + k]);
    }
    int i2 = idx - 36864;
    if (i2 >= 0 && i2 < 18432) {
        int j = i2 & 7, l = (i2 >> 3) & 63, s = i2 >> 9;
        int tt = s >> 2, kc = (s >> 1) & 1, mt = s & 1;
        int l15 = l & 15, quad = l >> 4;
        int m = mt * 16 + l15, c = kc * 32 + quad * 8 + j;
        unsigned short v = 0;
        if (m < NOFF) v = f2bf(w_off[((size_t)m * 64 + c) * 9 + tt]);
        wob_sw[i2] = v;
    }
}

// ---------------------------------------------------------------------------
// v16 = v13 (proven, 46.2us) templated for phase ablation.
//   MODE 0: real kernel, writes out (identical data path to v13).
//   MODE 1: front-end only (staging + offset conv + phase1 + shuffles),
//           digest -> scratch.   [isolates front-end cost]
//   MODE 2: no-gather (FETCH -> reuse of L regs), digest -> scratch.
//           [real - abl2 = gather cost]
//   MODE 3: no-interp (BFBUILD -> 3 XORs, all 4 gather rows stay live),
//           digest -> scratch.   [real - abl3 = interp VALU cost]
// Digests sum every acc element so no MFMA/load is DCE'd (rule #17).
// ---------------------------------------------------------------------------

#define BFBUILD(C, kc, BF, W0, W1, W2, W3)                                   \
    do {                                                                     \
        const unsigned* t0 = (const unsigned*)&(C)[(kc) * 4 + 0];            \
        const unsigned* t1 = (const unsigned*)&(C)[(kc) * 4 + 1];            \
        const unsigned* b0 = (const unsigned*)&(C)[(kc) * 4 + 2];            \
        const unsigned* b1 = (const unsigned*)&(C)[(kc) * 4 + 3];            \
        if constexpr (MODE == 3) {                                           \
            _Pragma("unroll")                                                \
            for (int jd = 0; jd < 4; ++jd)                                   \
                (BF).u[jd] = t0[jd] ^ t1[jd] ^ b0[jd] ^ b1[jd];              \
        } else {                                                             \
            _Pragma("unroll")                                                \
            for (int jd = 0; jd < 4; ++jd) {                                 \
                f32x2 t0p = {__uint_as_float(t0[jd] << 16),                  \
                             __uint_as_float(t0[jd] & 0xFFFF0000u)};         \
                f32x2 t1p = {__uint_as_float(t1[jd] << 16),                  \
                             __uint_as_float(t1[jd] & 0xFFFF0000u)};         \
                f32x2 b0p = {__uint_as_float(b0[jd] << 16),                  \
                             __uint_as_float(b0[jd] & 0xFFFF0000u)};         \
                f32x2 b1p = {__uint_as_float(b1[jd] << 16),                  \
                             __uint_as_float(b1[jd] & 0xFFFF0000u)};         \
                f32x2 vv = t0p * (W0) + t1p * (W1) + b0p * (W2) + b1p * (W3);\
                unsigned pk;                                                 \
                asm("v_cvt_pk_bf16_f32 %0, %1, %2"                           \
                    : "=v"(pk) : "v"(vv.x), "v"(vv.y));                      \
                (BF).u[jd] = pk;                                             \
            }                                                                \
        }                                                                    \
    } while (0)

#define TAP(k, SOFF)                                                         \
    do {                                                                     \
        const uint4* C = R[(k) & 1];                                         \
        union { unsigned u; __half2 hv; } c01, c23;                          \
        c01.u = pw01[(k)]; c23.u = pw23[(k)];                                \
        float W0 = __low2float(c01.hv), W1 = __high2float(c01.hv);           \
        float W2 = __low2float(c23.hv), W3 = __high2float(c23.hv);           \
        union { bf16x8 v; unsigned u[4]; } bfa, bfb;                         \
        BFBUILD(C, 0, bfa, W0, W1, W2, W3);                                  \
        BFBUILD(C, 1, bfb, W0, W1, W2, W3);                                  \
        _Pragma("unroll")                                                    \
        for (int ot = 0; ot < 4; ++ot) {                                     \
            bf16x8 af0 = s_w[(((k) * 2 + 0) * 4 + ot + (SOFF)) * 64 + lane]; \
            acc[ot] = __builtin_amdgcn_mfma_f32_16x16x32_bf16(               \
                af0, bfa.v, acc[ot], 0, 0, 0);                               \
            bf16x8 af1 = s_w[(((k) * 2 + 1) * 4 + ot + (SOFF)) * 64 + lane]; \
            acc[ot] = __builtin_amdgcn_mfma_f32_16x16x32_bf16(               \
                af1, bfb.v, acc[ot], 0, 0, 0);                               \
        }                                                                    \
    } while (0)

#define FETCH(kk, st)                                                \
    do {                                                             \
        if constexpr (MODE == 2) {                                   \
            _Pragma("unroll")                                        \
            for (int i_ = 0; i_ < 8; ++i_)                           \
                R[st][i_] = L[kk][i_ & 1];                           \
        } else {                                                     \
            R[st][0] = *(const uint4*)(xtb + at[kk] + co0);          \
            R[st][1] = *(const uint4*)(xtb + at[kk] + 64 + co0);     \
            R[st][2] = *(const uint4*)(xtb + ab[kk] + co0);          \
            R[st][3] = *(const uint4*)(xtb + ab[kk] + 64 + co0);     \
            R[st][4] = *(const uint4*)(xtb + at[kk] + co1);          \
            R[st][5] = *(const uint4*)(xtb + at[kk] + 64 + co1);     \
            R[st][6] = *(const uint4*)(xtb + ab[kk] + co1);          \
            R[st][7] = *(const uint4*)(xtb + ab[kk] + 64 + co1);     \
        }                                                            \
    } while (0)

template<int MODE>
__global__ __launch_bounds__(512, 4) void fused_deform_v16(
        const unsigned short* __restrict__ xt,
        const unsigned short* __restrict__ wob_sw,
        const unsigned short* __restrict__ wkb_sw,
        const float* __restrict__ b_off, float* __restrict__ out,
        float* __restrict__ scratch) {
    __shared__ bf16x8 s_w[40 * 64];         // 40960 B

    int gid  = blockIdx.x;                  // 512
    int xcd  = gid & 7;
    int j    = gid >> 3;
    int hh   = j & 15;
    int b    = j >> 4;
    int h    = xcd * 16 + hh;
    int tid  = threadIdx.x;
    int lane = tid & 63;
    int wave = __builtin_amdgcn_readfirstlane(tid >> 6);
    int l15  = lane & 15;
    int quad = lane >> 4;
    int p    = wave * 16 + l15;

    // ---- stage wob -> s_w[0..36) via DMA ----
    #pragma unroll
    for (int i = 0; i < 5; ++i) {
        int seg = i * 8 + wave;
        if (seg < 36) {
            int ebase = seg * 64;
            dma16((const uint4*)wob_sw + ebase + lane,
                  (char*)s_w + (size_t)ebase * 16);
        }
    }

    // ---- prefetch the 18 offset-tap fragments ----
    uint4 L[9][2];
    unsigned msk[9];
    const unsigned short* xtb = xt + (size_t)b * HW * 64;
    #pragma unroll
    for (int t9 = 0; t9 < 9; ++t9) {
        int ty = t9 / 3, tx = t9 % 3;
        int y  = h - 1 + ty;
        int xg = p - 1 + tx;
        bool v = (y >= 0) && (y < Hn) && (xg >= 0) && (xg < Wn);
        msk[t9] = v ? 0xFFFFFFFFu : 0u;
        int yc = min(max(y, 0), Hn - 1);
        int xc = min(max(xg, 0), Wn - 1);
        size_t base = ((size_t)yc * Wn + xc) * 64;
        L[t9][0] = *(const uint4*)(xtb + base + quad * 8);
        L[t9][1] = *(const uint4*)(xtb + base + 32 + quad * 8);
    }
    __syncthreads();                        // bar0

    // ---- offset conv: 36 MFMA ----
    f32x4 oa0 = (f32x4){0.f, 0.f, 0.f, 0.f};
    f32x4 oa1 = (f32x4){0.f, 0.f, 0.f, 0.f};
    #pragma unroll
    for (int t9 = 0; t9 < 9; ++t9) {
        unsigned m = msk[t9];
        #pragma unroll
        for (int kc = 0; kc < 2; ++kc) {
            union { bf16x8 v; uint4 u; } bf;
            bf.u = L[t9][kc];
            bf.u.x &= m; bf.u.y &= m; bf.u.z &= m; bf.u.w &= m;
            bf16x8 a0 = s_w[((t9 * 2 + kc) * 2 + 0) * 64 + lane];
            bf16x8 a1 = s_w[((t9 * 2 + kc) * 2 + 1) * 64 + lane];
            oa0 = __builtin_amdgcn_mfma_f32_16x16x32_bf16(a0, bf.v, oa0, 0, 0, 0);
            oa1 = __builtin_amdgcn_mfma_f32_16x16x32_bf16(a1, bf.v, oa1, 0, 0, 0);
        }
    }

    // ---- phase-1 ----
    unsigned my_ad[3]  = {0, 0, 0};
    unsigned my_w01[3] = {0, 0, 0};
    unsigned my_w23[3] = {0, 0, 0};
    auto phase1 = [&](int k, float dy, float dx, int slot) {
        float py  = (float)(h - 1 + k / 3) + dy;
        float pxf = (float)(p - 1 + k % 3) + dx;
        float y0f = floorf(py), x0f = floorf(pxf);
        float fy = py - y0f, fx = pxf - x0f;
        int y0 = (int)y0f, x0 = (int)x0f;
        bool vy0 = (y0 >= 0) & (y0 < Hn);
        bool vy1 = (y0 + 1 >= 0) & (y0 + 1 < Hn);
        bool vx0 = (x0 >= 0) & (x0 < Wn);
        bool vx1 = (x0 + 1 >= 0) & (x0 + 1 < Wn);
        float wy0 = vy0 ? 1.f - fy : 0.f;
        float wy1 = vy1 ? fy : 0.f;
        float wx0 = vx0 ? 1.f - fx : 0.f;
        float wx1 = vx1 ? fx : 0.f;
        int xc = min(max(x0, 0), Wn - 2);
        bool sel0 = (min(max(x0, 0), Wn - 1) != xc);
        bool sel1 = ((min(max(x0 + 1, 0), Wn - 1) - xc) == 1);
        float Wa = (sel0 ? 0.f : wx0) + (sel1 ? 0.f : wx1);
        float Wb = (sel0 ? wx0 : 0.f) + (sel1 ? wx1 : 0.f);
        int yc0 = min(max(y0, 0), Hn - 1), yc1 = min(max(y0 + 1, 0), Hn - 1);
        union { __half2 hv; unsigned u; } c01, c23;
        c01.hv = __floats2half2_rn(wy0 * Wa, wy0 * Wb);
        c23.hv = __floats2half2_rn(wy1 * Wa, wy1 * Wb);
        my_ad[slot]  = (unsigned)yc0 | ((unsigned)yc1 << 8) | ((unsigned)xc << 16);
        my_w01[slot] = c01.u;
        my_w23[slot] = c23.u;
    };
    int kb = quad * 2;
    phase1(kb,     oa0[0] + b_off[4 * quad],     oa0[1] + b_off[4 * quad + 1], 0);
    phase1(kb + 1, oa0[2] + b_off[4 * quad + 2], oa0[3] + b_off[4 * quad + 3], 1);
    if (quad == 0)
        phase1(8, oa1[0] + b_off[16], oa1[1] + b_off[17], 2);
    __syncthreads();                        // bar1

    // ---- stage wkb part A (taps 0..3, segs 0..31) ----
    #pragma unroll
    for (int i = 0; i < 4; ++i) {
        int seg = i * 8 + wave;
        dma16((const uint4*)wkb_sw + (size_t)seg * 64 + lane,
              (char*)s_w + (size_t)seg * 1024);
    }

    // ---- redistribute phase-1 via shuffles ----
    unsigned at[KKc], ab[KKc];
    unsigned pw01[KKc], pw23[KKc];
    #pragma unroll
    for (int k = 0; k < KKc; ++k) {
        int src  = (k < 8) ? ((k >> 1) * 16 + l15) : l15;
        int slot = (k < 8) ? (k & 1) : 2;
        unsigned ad  = (unsigned)__shfl((int)my_ad[slot],  src, 64);
        pw01[k] = (unsigned)__shfl((int)my_w01[slot], src, 64);
        pw23[k] = (unsigned)__shfl((int)my_w23[slot], src, 64);
        int xc = (int)(ad >> 16);
        at[k] = (unsigned)(((ad & 255u) * Wn + xc) * 64);
        ab[k] = (unsigned)((((ad >> 8) & 255u) * Wn + xc) * 64);
    }
    __syncthreads();                        // bar2: wkb-A visible

    if constexpr (MODE == 1) {              // front-end-only ablation exit
        unsigned d = 0;
        #pragma unroll
        for (int k = 0; k < KKc; ++k) d += at[k] + ab[k] + pw01[k] + pw23[k];
        scratch[(size_t)gid * 512 + tid] = (float)d;
        return;
    }

    f32x4 acc[4];
    #pragma unroll
    for (int ot = 0; ot < 4; ++ot) acc[ot] = (f32x4){0.f, 0.f, 0.f, 0.f};

    uint4 R[2][8];
    int co0 = quad * 8, co1 = 32 + quad * 8;

    // ---- main loop, part 1: taps 0..3 from wkb-A ----
    FETCH(0, 0);
    FETCH(1, 1); TAP(0, 0);
    FETCH(2, 0); TAP(1, 0);
    FETCH(3, 1); TAP(2, 0);
    FETCH(4, 0); TAP(3, 0);
    __syncthreads();                        // bar3

    // ---- stage wkb part B (segs 32..71 -> s_w[0..39]) ----
    #pragma unroll
    for (int i = 0; i < 5; ++i) {
        int seg = i * 8 + wave;
        dma16((const uint4*)wkb_sw + (size_t)(32 + seg) * 64 + lane,
              (char*)s_w + (size_t)seg * 1024);
    }

    // ---- tap-4 bridge ----
    union { bf16x8 v; unsigned u[4]; } bf40, bf41;
    {
        const uint4* C = R[0];
        union { unsigned u; __half2 hv; } c01, c23;
        c01.u = pw01[4]; c23.u = pw23[4];
        float W0 = __low2float(c01.hv), W1 = __high2float(c01.hv);
        float W2 = __low2float(c23.hv), W3 = __high2float(c23.hv);
        BFBUILD(C, 0, bf40, W0, W1, W2, W3);
        BFBUILD(C, 1, bf41, W0, W1, W2, W3);
    }
    FETCH(5, 1);
    __syncthreads();                        // bar4

    #pragma unroll
    for (int ot = 0; ot < 4; ++ot) {
        bf16x8 af0 = s_w[(0 + ot) * 64 + lane];
        acc[ot] = __builtin_amdgcn_mfma_f32_16x16x32_bf16(af0, bf40.v, acc[ot], 0, 0, 0);
        bf16x8 af1 = s_w[(4 + ot) * 64 + lane];
        acc[ot] = __builtin_amdgcn_mfma_f32_16x16x32_bf16(af1, bf41.v, acc[ot], 0, 0, 0);
    }

    // ---- main loop, part 2: taps 5..8 from wkb-B ----
    FETCH(6, 0); TAP(5, -32);
    FETCH(7, 1); TAP(6, -32);
    FETCH(8, 0); TAP(7, -32);
    TAP(8, -32);

    if constexpr (MODE == 0) {
        #pragma unroll
        for (int ot = 0; ot < 4; ++ot)
            #pragma unroll
            for (int r = 0; r < 4; ++r) {
                int o = ot * 16 + quad * 4 + r;
                out[(((size_t)b * COUTc + o) * Hn + h) * Wn + p] = acc[ot][r];
            }
    } else {
        float d = 0.f;                      // digest keeps all MFMAs live
        #pragma unroll
        for (int ot = 0; ot < 4; ++ot)
            #pragma unroll
            for (int r = 0; r < 4; ++r) d += acc[ot][r];
        scratch[(size_t)gid * 512 + tid] = d;
    }
}

// ---------------------------------------------------------------------------
extern "C" void kernel_launch(void* const* d_in, const int* in_sizes, int n_in,
                              void* d_out, int out_size, void* d_ws, size_t ws_size,
                              hipStream_t stream) {
    const float* x     = (const float*)d_in[0];
    const float* w_off = (const float*)d_in[1];
    const float* b_off = (const float*)d_in[2];
    const float* w_def = (const float*)d_in[3];
    float* out = (float*)d_out;

    char* ws = (char*)d_ws;
    unsigned short* xt = (unsigned short*)ws;                 // 8.39 MB
    ws += (size_t)Bn * HW * CINc * sizeof(unsigned short);
    unsigned short* wkb_sw = (unsigned short*)ws;             // 73728 B
    ws += 36864 * sizeof(unsigned short);
    unsigned short* wob_sw = (unsigned short*)ws;             // 36864 B
    ws += 36864;
    float* scratch = (float*)ws;                              // 1 MB digest

    prep_all<<<1024 + 216, 256, 0, stream>>>(x, xt, w_off, w_def, wkb_sw, wob_sw);
    // Real kernel first (comparable timing), ablations after into scratch.
    fused_deform_v16<0><<<Bn * Hn, 512, 0, stream>>>(xt, wob_sw, wkb_sw, b_off, out, scratch);
    fused_deform_v16<1><<<Bn * Hn, 512, 0, stream>>>(xt, wob_sw, wkb_sw, b_off, scratch, scratch);
    fused_deform_v16<2><<<Bn * Hn, 512, 0, stream>>>(xt, wob_sw, wkb_sw, b_off, scratch, scratch);
    fused_deform_v16<3><<<Bn * Hn, 512, 0, stream>>>(xt, wob_sw, wkb_sw, b_off, scratch, scratch);
}

// Round 10
// 120.887 us; speedup vs baseline: 1.5331x; 1.5331x over previous
//
#include <hip/hip_runtime.h>
#include <hip/hip_fp16.h>

#define Bn   4
#define CINc 64
#define COUTc 64
#define Hn   128
#define Wn   128
#define HW   (Hn * Wn)
#define KKc  9
#define NOFF 18

typedef short bf16x8 __attribute__((ext_vector_type(8)));
typedef float f32x4  __attribute__((ext_vector_type(4)));
typedef float f32x2  __attribute__((ext_vector_type(2)));

__device__ inline unsigned short f2bf(float f) {   // RNE fp32 -> bf16
    unsigned int u = __float_as_uint(f);
    return (unsigned short)((u + 0x7fffu + ((u >> 16) & 1u)) >> 16);
}

__device__ inline void dma16(const void* g, void* l) {
#if __has_builtin(__builtin_amdgcn_global_load_lds)
    __builtin_amdgcn_global_load_lds(
        (__attribute__((address_space(1))) void*)(g),
        (__attribute__((address_space(3))) void*)(l), 16, 0, 0);
#else
    *(uint4*)l = *(const uint4*)g;
#endif
}

// ---------------------------------------------------------------------------
// prep_all (v11 layout) — unchanged.
// ---------------------------------------------------------------------------
__global__ __launch_bounds__(256) void prep_all(
        const float* __restrict__ x, unsigned short* __restrict__ xt,
        const float* __restrict__ w_off, const float* __restrict__ w_def,
        unsigned short* __restrict__ wkb_sw, unsigned short* __restrict__ wob_sw) {
    int gb = blockIdx.x;
    int t  = threadIdx.x;
    if (gb < 1024) {
        __shared__ float s[64][65];
        int half = gb & 1;
        int h    = (gb >> 1) & 127;
        int b    = gb >> 8;
        int w0   = half * 64;
        int w = t & 63, cg = t >> 6;

        const float* xb = x + (size_t)b * CINc * HW + (size_t)h * Wn + w0 + w;
        #pragma unroll
        for (int i = 0; i < 16; ++i) {
            int c = cg * 16 + i;
            s[c][w] = xb[(size_t)c * HW];
        }
        __syncthreads();

        int cpair = t & 31, pxg = t >> 5;
        unsigned* xtp = (unsigned*)xt;
        #pragma unroll
        for (int i = 0; i < 8; ++i) {
            int px = pxg * 8 + i;
            float v0 = s[cpair * 2][px], v1 = s[cpair * 2 + 1][px];
            unsigned d = (unsigned)f2bf(v0) | ((unsigned)f2bf(v1) << 16);
            xtp[(((size_t)(b * Hn + h) * Wn) + w0 + px) * 32 + cpair] = d;
        }
        return;
    }
    int idx = (gb - 1024) * 256 + t;
    if (idx < 36864) {
        int j = idx & 7, l = (idx >> 3) & 63, s = idx >> 9;
        int k = s >> 3, kc = (s >> 2) & 1, ot = s & 3;
        int l15 = l & 15, quad = l >> 4;
        int o = ot * 16 + l15, c = kc * 32 + quad * 8 + j;
        wkb_sw[idx] = f2bf(w_def[((size_t)o * 64 + c) * 9 + k]);
    }
    int i2 = idx - 36864;
    if (i2 >= 0 && i2 < 18432) {
        int j = i2 & 7, l = (i2 >> 3) & 63, s = i2 >> 9;
        int tt = s >> 2, kc = (s >> 1) & 1, mt = s & 1;
        int l15 = l & 15, quad = l >> 4;
        int m = mt * 16 + l15, c = kc * 32 + quad * 8 + j;
        unsigned short v = 0;
        if (m < NOFF) v = f2bf(w_off[((size_t)m * 64 + c) * 9 + tt]);
        wob_sw[i2] = v;
    }
}

// ---------------------------------------------------------------------------
// v17: the v13 kernel split at the bar2 seam into two kernels.
// offs_k = v13 front-end verbatim (wob DMA + 18-tap prefetch + offset conv +
//   phase1), but instead of shuffle-redistribute it stores each lane's packed
//   phase-1 records (ad, w01, w23 — the exact u32s v13 shuffled) to global.
//   LDS 36.9KB only, VGPR ~52 -> fully resident in ONE generation.
// gmain = v13 main loop verbatim (wkb-A/B two-phase staging, FETCH/TAP,
//   identical BFBUILD data path), reading records instead of shuffling.
//   1024 blocks x 256 thr (b, h, half-row), 40KB LDS -> all-resident.
//   Front-end register state (L[9][2]+msk+oa = ~90 VGPR) is GONE, so the
//   main-loop live set (~120) fits the 128 cap -> compiler can finally
//   materialize the R[2][8] gather pipeline (v13 VGPR=52 proved it didn't).
// ---------------------------------------------------------------------------

#define BFBUILD(C, kc, BF, W0, W1, W2, W3)                                   \
    do {                                                                     \
        const unsigned* t0 = (const unsigned*)&(C)[(kc) * 4 + 0];            \
        const unsigned* t1 = (const unsigned*)&(C)[(kc) * 4 + 1];            \
        const unsigned* b0 = (const unsigned*)&(C)[(kc) * 4 + 2];            \
        const unsigned* b1 = (const unsigned*)&(C)[(kc) * 4 + 3];            \
        _Pragma("unroll")                                                    \
        for (int jd = 0; jd < 4; ++jd) {                                     \
            f32x2 t0p = {__uint_as_float(t0[jd] << 16),                      \
                         __uint_as_float(t0[jd] & 0xFFFF0000u)};             \
            f32x2 t1p = {__uint_as_float(t1[jd] << 16),                      \
                         __uint_as_float(t1[jd] & 0xFFFF0000u)};             \
            f32x2 b0p = {__uint_as_float(b0[jd] << 16),                      \
                         __uint_as_float(b0[jd] & 0xFFFF0000u)};             \
            f32x2 b1p = {__uint_as_float(b1[jd] << 16),                      \
                         __uint_as_float(b1[jd] & 0xFFFF0000u)};             \
            f32x2 vv = t0p * (W0) + t1p * (W1) + b0p * (W2) + b1p * (W3);    \
            unsigned pk;                                                     \
            asm("v_cvt_pk_bf16_f32 %0, %1, %2"                               \
                : "=v"(pk) : "v"(vv.x), "v"(vv.y));                          \
            (BF).u[jd] = pk;                                                 \
        }                                                                    \
    } while (0)

#define TAP(k, SOFF)                                                         \
    do {                                                                     \
        const uint4* C = R[(k) & 1];                                         \
        union { unsigned u; __half2 hv; } c01, c23;                          \
        c01.u = pw01[(k)]; c23.u = pw23[(k)];                                \
        float W0 = __low2float(c01.hv), W1 = __high2float(c01.hv);           \
        float W2 = __low2float(c23.hv), W3 = __high2float(c23.hv);           \
        union { bf16x8 v; unsigned u[4]; } bfa, bfb;                         \
        BFBUILD(C, 0, bfa, W0, W1, W2, W3);                                  \
        BFBUILD(C, 1, bfb, W0, W1, W2, W3);                                  \
        _Pragma("unroll")                                                    \
        for (int ot = 0; ot < 4; ++ot) {                                     \
            bf16x8 af0 = s_w[(((k) * 2 + 0) * 4 + ot + (SOFF)) * 64 + lane]; \
            acc[ot] = __builtin_amdgcn_mfma_f32_16x16x32_bf16(               \
                af0, bfa.v, acc[ot], 0, 0, 0);                               \
            bf16x8 af1 = s_w[(((k) * 2 + 1) * 4 + ot + (SOFF)) * 64 + lane]; \
            acc[ot] = __builtin_amdgcn_mfma_f32_16x16x32_bf16(               \
                af1, bfb.v, acc[ot], 0, 0, 0);                               \
        }                                                                    \
    } while (0)

// packed-ad decode inside FETCH (v12-verified), saves 9 persistent VGPRs
#define FETCH(kk, st)                                                \
    do {                                                             \
        unsigned ad_ = ad[kk];                                       \
        unsigned xc_ = ad_ >> 16;                                    \
        unsigned at_ = (((ad_ & 255u) << 7) + xc_) << 6;             \
        unsigned ab_ = ((((ad_ >> 8) & 255u) << 7) + xc_) << 6;      \
        R[st][0] = *(const uint4*)(xtb + at_ + co0);                 \
        R[st][1] = *(const uint4*)(xtb + at_ + 64 + co0);            \
        R[st][2] = *(const uint4*)(xtb + ab_ + co0);                 \
        R[st][3] = *(const uint4*)(xtb + ab_ + 64 + co0);            \
        R[st][4] = *(const uint4*)(xtb + at_ + co1);                 \
        R[st][5] = *(const uint4*)(xtb + at_ + 64 + co1);            \
        R[st][6] = *(const uint4*)(xtb + ab_ + co1);                 \
        R[st][7] = *(const uint4*)(xtb + ab_ + 64 + co1);            \
    } while (0)

// --------------------------- offset/front-end kernel -----------------------
__global__ __launch_bounds__(512, 4) void offs_k(
        const unsigned short* __restrict__ xt,
        const unsigned short* __restrict__ wob_sw,
        const float* __restrict__ b_off,
        unsigned* __restrict__ rec_ad, unsigned* __restrict__ rec_w01,
        unsigned* __restrict__ rec_w23) {
    __shared__ bf16x8 s_w[36 * 64];         // 36864 B (wob only)

    int gid  = blockIdx.x;                  // 512
    int xcd  = gid & 7;
    int j    = gid >> 3;
    int hh   = j & 15;
    int b    = j >> 4;
    int h    = xcd * 16 + hh;
    int tid  = threadIdx.x;
    int lane = tid & 63;
    int wave = __builtin_amdgcn_readfirstlane(tid >> 6);   // 0..7
    int l15  = lane & 15;
    int quad = lane >> 4;
    int p    = wave * 16 + l15;

    #pragma unroll
    for (int i = 0; i < 5; ++i) {
        int seg = i * 8 + wave;
        if (seg < 36) {
            int ebase = seg * 64;
            dma16((const uint4*)wob_sw + ebase + lane,
                  (char*)s_w + (size_t)ebase * 16);
        }
    }

    uint4 L[9][2];
    unsigned msk[9];
    const unsigned short* xtb = xt + (size_t)b * HW * 64;
    #pragma unroll
    for (int t9 = 0; t9 < 9; ++t9) {
        int ty = t9 / 3, tx = t9 % 3;
        int y  = h - 1 + ty;
        int xg = p - 1 + tx;
        bool v = (y >= 0) && (y < Hn) && (xg >= 0) && (xg < Wn);
        msk[t9] = v ? 0xFFFFFFFFu : 0u;
        int yc = min(max(y, 0), Hn - 1);
        int xc = min(max(xg, 0), Wn - 1);
        size_t base = ((size_t)yc * Wn + xc) * 64;
        L[t9][0] = *(const uint4*)(xtb + base + quad * 8);
        L[t9][1] = *(const uint4*)(xtb + base + 32 + quad * 8);
    }
    __syncthreads();                        // wob + prefetch drained

    f32x4 oa0 = (f32x4){0.f, 0.f, 0.f, 0.f};
    f32x4 oa1 = (f32x4){0.f, 0.f, 0.f, 0.f};
    #pragma unroll
    for (int t9 = 0; t9 < 9; ++t9) {
        unsigned m = msk[t9];
        #pragma unroll
        for (int kc = 0; kc < 2; ++kc) {
            union { bf16x8 v; uint4 u; } bf;
            bf.u = L[t9][kc];
            bf.u.x &= m; bf.u.y &= m; bf.u.z &= m; bf.u.w &= m;
            bf16x8 a0 = s_w[((t9 * 2 + kc) * 2 + 0) * 64 + lane];
            bf16x8 a1 = s_w[((t9 * 2 + kc) * 2 + 1) * 64 + lane];
            oa0 = __builtin_amdgcn_mfma_f32_16x16x32_bf16(a0, bf.v, oa0, 0, 0, 0);
            oa1 = __builtin_amdgcn_mfma_f32_16x16x32_bf16(a1, bf.v, oa1, 0, 0, 0);
        }
    }

    unsigned my_ad[3]  = {0, 0, 0};
    unsigned my_w01[3] = {0, 0, 0};
    unsigned my_w23[3] = {0, 0, 0};
    auto phase1 = [&](int k, float dy, float dx, int slot) {
        float py  = (float)(h - 1 + k / 3) + dy;
        float pxf = (float)(p - 1 + k % 3) + dx;
        float y0f = floorf(py), x0f = floorf(pxf);
        float fy = py - y0f, fx = pxf - x0f;
        int y0 = (int)y0f, x0 = (int)x0f;
        bool vy0 = (y0 >= 0) & (y0 < Hn);
        bool vy1 = (y0 + 1 >= 0) & (y0 + 1 < Hn);
        bool vx0 = (x0 >= 0) & (x0 < Wn);
        bool vx1 = (x0 + 1 >= 0) & (x0 + 1 < Wn);
        float wy0 = vy0 ? 1.f - fy : 0.f;
        float wy1 = vy1 ? fy : 0.f;
        float wx0 = vx0 ? 1.f - fx : 0.f;
        float wx1 = vx1 ? fx : 0.f;
        int xc = min(max(x0, 0), Wn - 2);
        bool sel0 = (min(max(x0, 0), Wn - 1) != xc);
        bool sel1 = ((min(max(x0 + 1, 0), Wn - 1) - xc) == 1);
        float Wa = (sel0 ? 0.f : wx0) + (sel1 ? 0.f : wx1);
        float Wb = (sel0 ? wx0 : 0.f) + (sel1 ? wx1 : 0.f);
        int yc0 = min(max(y0, 0), Hn - 1), yc1 = min(max(y0 + 1, 0), Hn - 1);
        union { __half2 hv; unsigned u; } c01, c23;
        c01.hv = __floats2half2_rn(wy0 * Wa, wy0 * Wb);
        c23.hv = __floats2half2_rn(wy1 * Wa, wy1 * Wb);
        my_ad[slot]  = (unsigned)yc0 | ((unsigned)yc1 << 8) | ((unsigned)xc << 16);
        my_w01[slot] = c01.u;
        my_w23[slot] = c23.u;
    };
    int kb = quad * 2;
    phase1(kb,     oa0[0] + b_off[4 * quad],     oa0[1] + b_off[4 * quad + 1], 0);
    phase1(kb + 1, oa0[2] + b_off[4 * quad + 2], oa0[3] + b_off[4 * quad + 3], 1);
    if (quad == 0)
        phase1(8, oa1[0] + b_off[16], oa1[1] + b_off[17], 2);

    // ---- store records (the exact u32s v13 shuffled): rec[((b,h),k),p] ----
    int rb = ((b * Hn + h) * KKc) * Wn + p;
    rec_ad [rb + kb * Wn]       = my_ad[0];
    rec_w01[rb + kb * Wn]       = my_w01[0];
    rec_w23[rb + kb * Wn]       = my_w23[0];
    rec_ad [rb + (kb + 1) * Wn] = my_ad[1];
    rec_w01[rb + (kb + 1) * Wn] = my_w01[1];
    rec_w23[rb + (kb + 1) * Wn] = my_w23[1];
    if (quad == 0) {
        rec_ad [rb + 8 * Wn] = my_ad[2];
        rec_w01[rb + 8 * Wn] = my_w01[2];
        rec_w23[rb + 8 * Wn] = my_w23[2];
    }
}

// --------------------------- gather/MFMA main kernel -----------------------
__global__ __launch_bounds__(256, 4) void gmain(
        const unsigned short* __restrict__ xt,
        const unsigned short* __restrict__ wkb_sw,
        const unsigned* __restrict__ rec_ad, const unsigned* __restrict__ rec_w01,
        const unsigned* __restrict__ rec_w23, float* __restrict__ out) {
    __shared__ bf16x8 s_w[40 * 64];         // 40960 B (wkb-A 32 / wkb-B 40)

    int gid  = blockIdx.x;                  // 1024
    int xcd  = gid & 7;
    int t2   = gid >> 3;                    // 0..127
    int wh   = t2 & 1;                      // half-row (both halves same XCD)
    int jj   = t2 >> 1;                     // 0..63
    int hh   = jj & 15;
    int b    = jj >> 4;
    int h    = xcd * 16 + hh;
    int tid  = threadIdx.x;
    int lane = tid & 63;
    int wave = __builtin_amdgcn_readfirstlane(tid >> 6);   // 0..3
    int l15  = lane & 15;
    int quad = lane >> 4;
    int p    = wh * 64 + wave * 16 + l15;   // pixel col (0..127)

    // ---- stage wkb-A (segs 0..31) over 4 waves ----
    #pragma unroll
    for (int i = 0; i < 8; ++i) {
        int seg = i * 4 + wave;
        dma16((const uint4*)wkb_sw + (size_t)seg * 64 + lane,
              (char*)s_w + (size_t)seg * 1024);
    }

    // ---- load phase-1 records (9 taps x 3 u32, all independent loads) ----
    const unsigned short* xtb = xt + (size_t)b * HW * 64;
    unsigned ad[KKc], pw01[KKc], pw23[KKc];
    int rb = ((b * Hn + h) * KKc) * Wn + p;
    #pragma unroll
    for (int k = 0; k < KKc; ++k) {
        ad[k]   = rec_ad [rb + k * Wn];
        pw01[k] = rec_w01[rb + k * Wn];
        pw23[k] = rec_w23[rb + k * Wn];
    }
    __syncthreads();                        // wkb-A visible

    f32x4 acc[4];
    #pragma unroll
    for (int ot = 0; ot < 4; ++ot) acc[ot] = (f32x4){0.f, 0.f, 0.f, 0.f};

    uint4 R[2][8];
    int co0 = quad * 8, co1 = 32 + quad * 8;

    // ---- main loop, part 1: taps 0..3 from wkb-A (v13 sequence verbatim) --
    FETCH(0, 0);
    FETCH(1, 1); TAP(0, 0);
    FETCH(2, 0); TAP(1, 0);
    FETCH(3, 1); TAP(2, 0);
    FETCH(4, 0); TAP(3, 0);
    __syncthreads();                        // all wkb-A reads done

    // ---- stage wkb-B (segs 32..71 -> s_w[0..39]) over 4 waves ----
    #pragma unroll
    for (int i = 0; i < 10; ++i) {
        int seg = i * 4 + wave;
        dma16((const uint4*)wkb_sw + (size_t)(32 + seg) * 64 + lane,
              (char*)s_w + (size_t)seg * 1024);
    }

    // ---- tap-4 bridge: interp VALU covers the wkb-B DMA flight ----
    union { bf16x8 v; unsigned u[4]; } bf40, bf41;
    {
        const uint4* C = R[0];
        union { unsigned u; __half2 hv; } c01, c23;
        c01.u = pw01[4]; c23.u = pw23[4];
        float W0 = __low2float(c01.hv), W1 = __high2float(c01.hv);
        float W2 = __low2float(c23.hv), W3 = __high2float(c23.hv);
        BFBUILD(C, 0, bf40, W0, W1, W2, W3);
        BFBUILD(C, 1, bf41, W0, W1, W2, W3);
    }
    FETCH(5, 1);
    __syncthreads();                        // wkb-B visible

    #pragma unroll
    for (int ot = 0; ot < 4; ++ot) {        // tap 4: segs 32..39 -> 0..7
        bf16x8 af0 = s_w[(0 + ot) * 64 + lane];
        acc[ot] = __builtin_amdgcn_mfma_f32_16x16x32_bf16(af0, bf40.v, acc[ot], 0, 0, 0);
        bf16x8 af1 = s_w[(4 + ot) * 64 + lane];
        acc[ot] = __builtin_amdgcn_mfma_f32_16x16x32_bf16(af1, bf41.v, acc[ot], 0, 0, 0);
    }

    // ---- main loop, part 2: taps 5..8 from wkb-B ----
    FETCH(6, 0); TAP(5, -32);
    FETCH(7, 1); TAP(6, -32);
    FETCH(8, 0); TAP(7, -32);
    TAP(8, -32);

    #pragma unroll
    for (int ot = 0; ot < 4; ++ot)
        #pragma unroll
        for (int r = 0; r < 4; ++r) {
            int o = ot * 16 + quad * 4 + r;
            out[(((size_t)b * COUTc + o) * Hn + h) * Wn + p] = acc[ot][r];
        }
}

// ---------------------------------------------------------------------------
extern "C" void kernel_launch(void* const* d_in, const int* in_sizes, int n_in,
                              void* d_out, int out_size, void* d_ws, size_t ws_size,
                              hipStream_t stream) {
    const float* x     = (const float*)d_in[0];
    const float* w_off = (const float*)d_in[1];
    const float* b_off = (const float*)d_in[2];
    const float* w_def = (const float*)d_in[3];
    float* out = (float*)d_out;

    char* ws = (char*)d_ws;
    unsigned short* xt = (unsigned short*)ws;                 // 8.39 MB
    ws += (size_t)Bn * HW * CINc * sizeof(unsigned short);
    unsigned short* wkb_sw = (unsigned short*)ws;             // 73728 B
    ws += 36864 * sizeof(unsigned short);
    unsigned short* wob_sw = (unsigned short*)ws;             // 36864 B
    ws += 36864;
    unsigned* rec_ad = (unsigned*)ws;                         // 2.36 MB
    ws += (size_t)Bn * Hn * KKc * Wn * 4;
    unsigned* rec_w01 = (unsigned*)ws;                        // 2.36 MB
    ws += (size_t)Bn * Hn * KKc * Wn * 4;
    unsigned* rec_w23 = (unsigned*)ws;                        // 2.36 MB

    prep_all<<<1024 + 216, 256, 0, stream>>>(x, xt, w_off, w_def, wkb_sw, wob_sw);
    offs_k<<<Bn * Hn, 512, 0, stream>>>(xt, wob_sw, b_off, rec_ad, rec_w01, rec_w23);
    gmain<<<Bn * Hn * 2, 256, 0, stream>>>(xt, wkb_sw, rec_ad, rec_w01, rec_w23, out);
}

// Round 11
// 116.909 us; speedup vs baseline: 1.5853x; 1.0340x over previous
//
#include <hip/hip_runtime.h>
#include <hip/hip_fp16.h>

#define Bn   4
#define CINc 64
#define COUTc 64
#define Hn   128
#define Wn   128
#define HW   (Hn * Wn)
#define KKc  9
#define NOFF 18

typedef short bf16x8 __attribute__((ext_vector_type(8)));
typedef float f32x4  __attribute__((ext_vector_type(4)));
typedef float f32x2  __attribute__((ext_vector_type(2)));

__device__ inline unsigned short f2bf(float f) {   // RNE fp32 -> bf16
    unsigned int u = __float_as_uint(f);
    return (unsigned short)((u + 0x7fffu + ((u >> 16) & 1u)) >> 16);
}

__device__ inline void dma16(const void* g, void* l) {
#if __has_builtin(__builtin_amdgcn_global_load_lds)
    __builtin_amdgcn_global_load_lds(
        (__attribute__((address_space(1))) void*)(g),
        (__attribute__((address_space(3))) void*)(l), 16, 0, 0);
#else
    *(uint4*)l = *(const uint4*)g;
#endif
}

// ---------------------------------------------------------------------------
// prep_all v18: transpose loads vectorized (4x float4 per thread, was 16
// scalar). LDS write banks: (65c + 4w + j) -> 2-way alias = free. Pack phase
// and weight-table blocks unchanged (v11 layout).
// ---------------------------------------------------------------------------
__global__ __launch_bounds__(256) void prep_all(
        const float* __restrict__ x, unsigned short* __restrict__ xt,
        const float* __restrict__ w_off, const float* __restrict__ w_def,
        unsigned short* __restrict__ wkb_sw, unsigned short* __restrict__ wob_sw) {
    int gb = blockIdx.x;
    int t  = threadIdx.x;
    if (gb < 1024) {
        __shared__ float s[64][65];
        int half = gb & 1;
        int h    = (gb >> 1) & 127;
        int b    = gb >> 8;
        int w0   = half * 64;

        const float* xb = x + (size_t)b * CINc * HW + (size_t)h * Wn + w0;
        int c0 = t >> 4, wq = (t & 15) * 4;
        #pragma unroll
        for (int i = 0; i < 4; ++i) {
            int c = c0 + i * 16;
            float4 v = *(const float4*)(xb + (size_t)c * HW + wq);
            s[c][wq]     = v.x;
            s[c][wq + 1] = v.y;
            s[c][wq + 2] = v.z;
            s[c][wq + 3] = v.w;
        }
        __syncthreads();

        int cpair = t & 31, pxg = t >> 5;
        unsigned* xtp = (unsigned*)xt;
        #pragma unroll
        for (int i = 0; i < 8; ++i) {
            int px = pxg * 8 + i;
            float v0 = s[cpair * 2][px], v1 = s[cpair * 2 + 1][px];
            unsigned d = (unsigned)f2bf(v0) | ((unsigned)f2bf(v1) << 16);
            xtp[(((size_t)(b * Hn + h) * Wn) + w0 + px) * 32 + cpair] = d;
        }
        return;
    }
    int idx = (gb - 1024) * 256 + t;
    if (idx < 36864) {
        int j = idx & 7, l = (idx >> 3) & 63, s = idx >> 9;
        int k = s >> 3, kc = (s >> 2) & 1, ot = s & 3;
        int l15 = l & 15, quad = l >> 4;
        int o = ot * 16 + l15, c = kc * 32 + quad * 8 + j;
        wkb_sw[idx] = f2bf(w_def[((size_t)o * 64 + c) * 9 + k]);
    }
    int i2 = idx - 36864;
    if (i2 >= 0 && i2 < 18432) {
        int j = i2 & 7, l = (i2 >> 3) & 63, s = i2 >> 9;
        int tt = s >> 2, kc = (s >> 1) & 1, mt = s & 1;
        int l15 = l & 15, quad = l >> 4;
        int m = mt * 16 + l15, c = kc * 32 + quad * 8 + j;
        unsigned short v = 0;
        if (m < NOFF) v = f2bf(w_off[((size_t)m * 64 + c) * 9 + tt]);
        wob_sw[i2] = v;
    }
}

// ---------------------------------------------------------------------------
// Fused deformable conv v18: v13's exact data path at HALF-ROW granularity.
// 1024 blocks x 256 thr (b, h, half-row), LDS 36864 B (wob 36 segs; wkb
// staged in 3 phases A=taps0-3/32segs, B=taps4-7/32, C=tap8/8, all <=36).
// 4 blocks/CU x 147.5KB LDS -> ALL 1024 blocks resident in ONE generation,
// 16 waves/CU (v13: 8). No front-end duplication: each half-row block does
// phase1 for its own 64 px. Tests the wave-starvation theory cleanly.
// ---------------------------------------------------------------------------

#define BFBUILD(C, kc, BF, W0, W1, W2, W3)                                   \
    do {                                                                     \
        const unsigned* t0 = (const unsigned*)&(C)[(kc) * 4 + 0];            \
        const unsigned* t1 = (const unsigned*)&(C)[(kc) * 4 + 1];            \
        const unsigned* b0 = (const unsigned*)&(C)[(kc) * 4 + 2];            \
        const unsigned* b1 = (const unsigned*)&(C)[(kc) * 4 + 3];            \
        _Pragma("unroll")                                                    \
        for (int jd = 0; jd < 4; ++jd) {                                     \
            f32x2 t0p = {__uint_as_float(t0[jd] << 16),                      \
                         __uint_as_float(t0[jd] & 0xFFFF0000u)};             \
            f32x2 t1p = {__uint_as_float(t1[jd] << 16),                      \
                         __uint_as_float(t1[jd] & 0xFFFF0000u)};             \
            f32x2 b0p = {__uint_as_float(b0[jd] << 16),                      \
                         __uint_as_float(b0[jd] & 0xFFFF0000u)};             \
            f32x2 b1p = {__uint_as_float(b1[jd] << 16),                      \
                         __uint_as_float(b1[jd] & 0xFFFF0000u)};             \
            f32x2 vv = t0p * (W0) + t1p * (W1) + b0p * (W2) + b1p * (W3);    \
            unsigned pk;                                                     \
            asm("v_cvt_pk_bf16_f32 %0, %1, %2"                               \
                : "=v"(pk) : "v"(vv.x), "v"(vv.y));                          \
            (BF).u[jd] = pk;                                                 \
        }                                                                    \
    } while (0)

#define TAP(k, SOFF)                                                         \
    do {                                                                     \
        const uint4* C = R[(k) & 1];                                         \
        union { unsigned u; __half2 hv; } c01, c23;                          \
        c01.u = pw01[(k)]; c23.u = pw23[(k)];                                \
        float W0 = __low2float(c01.hv), W1 = __high2float(c01.hv);           \
        float W2 = __low2float(c23.hv), W3 = __high2float(c23.hv);           \
        union { bf16x8 v; unsigned u[4]; } bfa, bfb;                         \
        BFBUILD(C, 0, bfa, W0, W1, W2, W3);                                  \
        BFBUILD(C, 1, bfb, W0, W1, W2, W3);                                  \
        _Pragma("unroll")                                                    \
        for (int ot = 0; ot < 4; ++ot) {                                     \
            bf16x8 af0 = s_w[(((k) * 2 + 0) * 4 + ot + (SOFF)) * 64 + lane]; \
            acc[ot] = __builtin_amdgcn_mfma_f32_16x16x32_bf16(               \
                af0, bfa.v, acc[ot], 0, 0, 0);                               \
            bf16x8 af1 = s_w[(((k) * 2 + 1) * 4 + ot + (SOFF)) * 64 + lane]; \
            acc[ot] = __builtin_amdgcn_mfma_f32_16x16x32_bf16(               \
                af1, bfb.v, acc[ot], 0, 0, 0);                               \
        }                                                                    \
    } while (0)

#define FETCH(kk, st)                                                \
    do {                                                             \
        unsigned ad_ = ad[kk];                                       \
        unsigned xc_ = ad_ >> 16;                                    \
        unsigned at_ = (((ad_ & 255u) << 7) + xc_) << 6;             \
        unsigned ab_ = ((((ad_ >> 8) & 255u) << 7) + xc_) << 6;      \
        R[st][0] = *(const uint4*)(xtb + at_ + co0);                 \
        R[st][1] = *(const uint4*)(xtb + at_ + 64 + co0);            \
        R[st][2] = *(const uint4*)(xtb + ab_ + co0);                 \
        R[st][3] = *(const uint4*)(xtb + ab_ + 64 + co0);            \
        R[st][4] = *(const uint4*)(xtb + at_ + co1);                 \
        R[st][5] = *(const uint4*)(xtb + at_ + 64 + co1);            \
        R[st][6] = *(const uint4*)(xtb + ab_ + co1);                 \
        R[st][7] = *(const uint4*)(xtb + ab_ + 64 + co1);            \
    } while (0)

__global__ __launch_bounds__(256, 4) void fused_deform_v18(
        const unsigned short* __restrict__ xt,
        const unsigned short* __restrict__ wob_sw,
        const unsigned short* __restrict__ wkb_sw,
        const float* __restrict__ b_off, float* __restrict__ out) {
    __shared__ bf16x8 s_w[36 * 64];         // 36864 B

    int gid  = blockIdx.x;                  // 1024
    int xcd  = gid & 7;
    int r    = gid >> 3;                    // 0..127
    int wh   = r & 1;                       // half-row
    int j    = r >> 1;                      // 0..63
    int hh   = j & 15;
    int b    = j >> 4;
    int h    = xcd * 16 + hh;
    int tid  = threadIdx.x;
    int lane = tid & 63;
    int wave = __builtin_amdgcn_readfirstlane(tid >> 6);   // 0..3
    int l15  = lane & 15;
    int quad = lane >> 4;
    int p    = wh * 64 + wave * 16 + l15;   // pixel col (0..127)

    // ---- stage wob -> s_w[0..36) via DMA (9 segs per wave) ----
    #pragma unroll
    for (int i = 0; i < 9; ++i) {
        int seg = i * 4 + wave;
        int ebase = seg * 64;
        dma16((const uint4*)wob_sw + ebase + lane,
              (char*)s_w + (size_t)ebase * 16);
    }

    // ---- prefetch the 18 offset-tap fragments ----
    uint4 L[9][2];
    unsigned msk[9];
    const unsigned short* xtb = xt + (size_t)b * HW * 64;
    #pragma unroll
    for (int t9 = 0; t9 < 9; ++t9) {
        int ty = t9 / 3, tx = t9 % 3;
        int y  = h - 1 + ty;
        int xg = p - 1 + tx;
        bool v = (y >= 0) && (y < Hn) && (xg >= 0) && (xg < Wn);
        msk[t9] = v ? 0xFFFFFFFFu : 0u;
        int yc = min(max(y, 0), Hn - 1);
        int xc = min(max(xg, 0), Wn - 1);
        size_t base = ((size_t)yc * Wn + xc) * 64;
        L[t9][0] = *(const uint4*)(xtb + base + quad * 8);
        L[t9][1] = *(const uint4*)(xtb + base + 32 + quad * 8);
    }
    __syncthreads();                        // bar0: wob DMA + prefetch drained

    // ---- offset conv: 36 MFMA ----
    f32x4 oa0 = (f32x4){0.f, 0.f, 0.f, 0.f};
    f32x4 oa1 = (f32x4){0.f, 0.f, 0.f, 0.f};
    #pragma unroll
    for (int t9 = 0; t9 < 9; ++t9) {
        unsigned m = msk[t9];
        #pragma unroll
        for (int kc = 0; kc < 2; ++kc) {
            union { bf16x8 v; uint4 u; } bf;
            bf.u = L[t9][kc];
            bf.u.x &= m; bf.u.y &= m; bf.u.z &= m; bf.u.w &= m;
            bf16x8 a0 = s_w[((t9 * 2 + kc) * 2 + 0) * 64 + lane];
            bf16x8 a1 = s_w[((t9 * 2 + kc) * 2 + 1) * 64 + lane];
            oa0 = __builtin_amdgcn_mfma_f32_16x16x32_bf16(a0, bf.v, oa0, 0, 0, 0);
            oa1 = __builtin_amdgcn_mfma_f32_16x16x32_bf16(a1, bf.v, oa1, 0, 0, 0);
        }
    }

    // ---- phase-1 (per-wave 16 px; quad owns taps 2q,2q+1; quad0 tap8) ----
    unsigned my_ad[3]  = {0, 0, 0};
    unsigned my_w01[3] = {0, 0, 0};
    unsigned my_w23[3] = {0, 0, 0};
    auto phase1 = [&](int k, float dy, float dx, int slot) {
        float py  = (float)(h - 1 + k / 3) + dy;
        float pxf = (float)(p - 1 + k % 3) + dx;
        float y0f = floorf(py), x0f = floorf(pxf);
        float fy = py - y0f, fx = pxf - x0f;
        int y0 = (int)y0f, x0 = (int)x0f;
        bool vy0 = (y0 >= 0) & (y0 < Hn);
        bool vy1 = (y0 + 1 >= 0) & (y0 + 1 < Hn);
        bool vx0 = (x0 >= 0) & (x0 < Wn);
        bool vx1 = (x0 + 1 >= 0) & (x0 + 1 < Wn);
        float wy0 = vy0 ? 1.f - fy : 0.f;
        float wy1 = vy1 ? fy : 0.f;
        float wx0 = vx0 ? 1.f - fx : 0.f;
        float wx1 = vx1 ? fx : 0.f;
        int xc = min(max(x0, 0), Wn - 2);
        bool sel0 = (min(max(x0, 0), Wn - 1) != xc);
        bool sel1 = ((min(max(x0 + 1, 0), Wn - 1) - xc) == 1);
        float Wa = (sel0 ? 0.f : wx0) + (sel1 ? 0.f : wx1);
        float Wb = (sel0 ? wx0 : 0.f) + (sel1 ? wx1 : 0.f);
        int yc0 = min(max(y0, 0), Hn - 1), yc1 = min(max(y0 + 1, 0), Hn - 1);
        union { __half2 hv; unsigned u; } c01, c23;
        c01.hv = __floats2half2_rn(wy0 * Wa, wy0 * Wb);
        c23.hv = __floats2half2_rn(wy1 * Wa, wy1 * Wb);
        my_ad[slot]  = (unsigned)yc0 | ((unsigned)yc1 << 8) | ((unsigned)xc << 16);
        my_w01[slot] = c01.u;
        my_w23[slot] = c23.u;
    };
    int kb = quad * 2;
    phase1(kb,     oa0[0] + b_off[4 * quad],     oa0[1] + b_off[4 * quad + 1], 0);
    phase1(kb + 1, oa0[2] + b_off[4 * quad + 2], oa0[3] + b_off[4 * quad + 3], 1);
    if (quad == 0)
        phase1(8, oa1[0] + b_off[16], oa1[1] + b_off[17], 2);
    __syncthreads();                        // bar1: all wob ds_reads done

    // ---- stage wkb-A (taps 0..3 = segs 0..31) ----
    #pragma unroll
    for (int i = 0; i < 8; ++i) {
        int seg = i * 4 + wave;
        dma16((const uint4*)wkb_sw + (size_t)seg * 64 + lane,
              (char*)s_w + (size_t)seg * 1024);
    }

    // ---- redistribute phase-1 via shuffles (wave-local) ----
    unsigned ad[KKc], pw01[KKc], pw23[KKc];
    #pragma unroll
    for (int k = 0; k < KKc; ++k) {
        int src  = (k < 8) ? ((k >> 1) * 16 + l15) : l15;
        int slot = (k < 8) ? (k & 1) : 2;
        ad[k]   = (unsigned)__shfl((int)my_ad[slot],  src, 64);
        pw01[k] = (unsigned)__shfl((int)my_w01[slot], src, 64);
        pw23[k] = (unsigned)__shfl((int)my_w23[slot], src, 64);
    }
    __syncthreads();                        // bar2: wkb-A visible

    f32x4 acc[4];
    #pragma unroll
    for (int ot = 0; ot < 4; ++ot) acc[ot] = (f32x4){0.f, 0.f, 0.f, 0.f};

    uint4 R[2][8];
    int co0 = quad * 8, co1 = 32 + quad * 8;

    // ---- part 1: taps 0..3 from wkb-A ----
    FETCH(0, 0);
    FETCH(1, 1); TAP(0, 0);
    FETCH(2, 0); TAP(1, 0);
    FETCH(3, 1); TAP(2, 0);
    FETCH(4, 0); TAP(3, 0);
    __syncthreads();                        // bar3: wkb-A reads done

    // ---- stage wkb-B (taps 4..7 = segs 32..63 -> s_w[0..31]) ----
    #pragma unroll
    for (int i = 0; i < 8; ++i) {
        int seg = i * 4 + wave;
        dma16((const uint4*)wkb_sw + (size_t)(32 + seg) * 64 + lane,
              (char*)s_w + (size_t)seg * 1024);
    }

    // ---- tap-4 bridge: interp VALU covers the B-DMA flight ----
    union { bf16x8 v; unsigned u[4]; } bf40, bf41;
    {
        const uint4* C = R[0];
        union { unsigned u; __half2 hv; } c01, c23;
        c01.u = pw01[4]; c23.u = pw23[4];
        float W0 = __low2float(c01.hv), W1 = __high2float(c01.hv);
        float W2 = __low2float(c23.hv), W3 = __high2float(c23.hv);
        BFBUILD(C, 0, bf40, W0, W1, W2, W3);
        BFBUILD(C, 1, bf41, W0, W1, W2, W3);
    }
    FETCH(5, 1);
    __syncthreads();                        // bar4: wkb-B visible

    #pragma unroll
    for (int ot = 0; ot < 4; ++ot) {        // tap 4: local segs 0..7
        bf16x8 af0 = s_w[(0 + ot) * 64 + lane];
        acc[ot] = __builtin_amdgcn_mfma_f32_16x16x32_bf16(af0, bf40.v, acc[ot], 0, 0, 0);
        bf16x8 af1 = s_w[(4 + ot) * 64 + lane];
        acc[ot] = __builtin_amdgcn_mfma_f32_16x16x32_bf16(af1, bf41.v, acc[ot], 0, 0, 0);
    }

    // ---- part 2: taps 5..7 from wkb-B (local = global-32) ----
    FETCH(6, 0); TAP(5, -32);
    FETCH(7, 1); TAP(6, -32);
    FETCH(8, 0); TAP(7, -32);
    __syncthreads();                        // bar5: wkb-B reads done

    // ---- stage wkb-C (tap 8 = segs 64..71 -> s_w[0..7]) ----
    #pragma unroll
    for (int i = 0; i < 2; ++i) {
        int seg = i * 4 + wave;
        dma16((const uint4*)wkb_sw + (size_t)(64 + seg) * 64 + lane,
              (char*)s_w + (size_t)seg * 1024);
    }

    // ---- tap-8 bridge: interp covers C-DMA flight ----
    union { bf16x8 v; unsigned u[4]; } bf80, bf81;
    {
        const uint4* C = R[0];              // FETCH(8,0)
        union { unsigned u; __half2 hv; } c01, c23;
        c01.u = pw01[8]; c23.u = pw23[8];
        float W0 = __low2float(c01.hv), W1 = __high2float(c01.hv);
        float W2 = __low2float(c23.hv), W3 = __high2float(c23.hv);
        BFBUILD(C, 0, bf80, W0, W1, W2, W3);
        BFBUILD(C, 1, bf81, W0, W1, W2, W3);
    }
    __syncthreads();                        // bar6: wkb-C visible

    #pragma unroll
    for (int ot = 0; ot < 4; ++ot) {        // tap 8: local segs 0..7
        bf16x8 af0 = s_w[(0 + ot) * 64 + lane];
        acc[ot] = __builtin_amdgcn_mfma_f32_16x16x32_bf16(af0, bf80.v, acc[ot], 0, 0, 0);
        bf16x8 af1 = s_w[(4 + ot) * 64 + lane];
        acc[ot] = __builtin_amdgcn_mfma_f32_16x16x32_bf16(af1, bf81.v, acc[ot], 0, 0, 0);
    }

    #pragma unroll
    for (int ot = 0; ot < 4; ++ot)
        #pragma unroll
        for (int rr = 0; rr < 4; ++rr) {
            int o = ot * 16 + quad * 4 + rr;
            out[(((size_t)b * COUTc + o) * Hn + h) * Wn + p] = acc[ot][rr];
        }
}

// ---------------------------------------------------------------------------
extern "C" void kernel_launch(void* const* d_in, const int* in_sizes, int n_in,
                              void* d_out, int out_size, void* d_ws, size_t ws_size,
                              hipStream_t stream) {
    const float* x     = (const float*)d_in[0];
    const float* w_off = (const float*)d_in[1];
    const float* b_off = (const float*)d_in[2];
    const float* w_def = (const float*)d_in[3];
    float* out = (float*)d_out;

    char* ws = (char*)d_ws;
    unsigned short* xt = (unsigned short*)ws;                 // 8.39 MB
    ws += (size_t)Bn * HW * CINc * sizeof(unsigned short);
    unsigned short* wkb_sw = (unsigned short*)ws;             // 73728 B
    ws += 36864 * sizeof(unsigned short);
    unsigned short* wob_sw = (unsigned short*)ws;             // 36864 B

    prep_all<<<1024 + 216, 256, 0, stream>>>(x, xt, w_off, w_def, wkb_sw, wob_sw);
    fused_deform_v18<<<Bn * Hn * 2, 256, 0, stream>>>(xt, wob_sw, wkb_sw, b_off, out);
}

// Round 12
// 116.452 us; speedup vs baseline: 1.5915x; 1.0039x over previous
//
#include <hip/hip_runtime.h>
#include <hip/hip_fp16.h>

#define Bn   4
#define CINc 64
#define COUTc 64
#define Hn   128
#define Wn   128
#define HW   (Hn * Wn)
#define KKc  9
#define NOFF 18

typedef short bf16x8 __attribute__((ext_vector_type(8)));
typedef float f32x4  __attribute__((ext_vector_type(4)));
typedef float f32x2  __attribute__((ext_vector_type(2)));

__device__ inline unsigned short f2bf(float f) {   // RNE fp32 -> bf16
    unsigned int u = __float_as_uint(f);
    return (unsigned short)((u + 0x7fffu + ((u >> 16) & 1u)) >> 16);
}

__device__ inline void dma16(const void* g, void* l) {
#if __has_builtin(__builtin_amdgcn_global_load_lds)
    __builtin_amdgcn_global_load_lds(
        (__attribute__((address_space(1))) void*)(g),
        (__attribute__((address_space(3))) void*)(l), 16, 0, 0);
#else
    *(uint4*)l = *(const uint4*)g;
#endif
}

// ---------------------------------------------------------------------------
// prep_all (v18: vectorized transpose loads) — unchanged from round 10.
// ---------------------------------------------------------------------------
__global__ __launch_bounds__(256) void prep_all(
        const float* __restrict__ x, unsigned short* __restrict__ xt,
        const float* __restrict__ w_off, const float* __restrict__ w_def,
        unsigned short* __restrict__ wkb_sw, unsigned short* __restrict__ wob_sw) {
    int gb = blockIdx.x;
    int t  = threadIdx.x;
    if (gb < 1024) {
        __shared__ float s[64][65];
        int half = gb & 1;
        int h    = (gb >> 1) & 127;
        int b    = gb >> 8;
        int w0   = half * 64;

        const float* xb = x + (size_t)b * CINc * HW + (size_t)h * Wn + w0;
        int c0 = t >> 4, wq = (t & 15) * 4;
        #pragma unroll
        for (int i = 0; i < 4; ++i) {
            int c = c0 + i * 16;
            float4 v = *(const float4*)(xb + (size_t)c * HW + wq);
            s[c][wq]     = v.x;
            s[c][wq + 1] = v.y;
            s[c][wq + 2] = v.z;
            s[c][wq + 3] = v.w;
        }
        __syncthreads();

        int cpair = t & 31, pxg = t >> 5;
        unsigned* xtp = (unsigned*)xt;
        #pragma unroll
        for (int i = 0; i < 8; ++i) {
            int px = pxg * 8 + i;
            float v0 = s[cpair * 2][px], v1 = s[cpair * 2 + 1][px];
            unsigned d = (unsigned)f2bf(v0) | ((unsigned)f2bf(v1) << 16);
            xtp[(((size_t)(b * Hn + h) * Wn) + w0 + px) * 32 + cpair] = d;
        }
        return;
    }
    int idx = (gb - 1024) * 256 + t;
    if (idx < 36864) {
        int j = idx & 7, l = (idx >> 3) & 63, s = idx >> 9;
        int k = s >> 3, kc = (s >> 2) & 1, ot = s & 3;
        int l15 = l & 15, quad = l >> 4;
        int o = ot * 16 + l15, c = kc * 32 + quad * 8 + j;
        wkb_sw[idx] = f2bf(w_def[((size_t)o * 64 + c) * 9 + k]);
    }
    int i2 = idx - 36864;
    if (i2 >= 0 && i2 < 18432) {
        int j = i2 & 7, l = (i2 >> 3) & 63, s = i2 >> 9;
        int tt = s >> 2, kc = (s >> 1) & 1, mt = s & 1;
        int l15 = l & 15, quad = l >> 4;
        int m = mt * 16 + l15, c = kc * 32 + quad * 8 + j;
        unsigned short v = 0;
        if (m < NOFF) v = f2bf(w_off[((size_t)m * 64 + c) * 9 + tt]);
        wob_sw[i2] = v;
    }
}

// ---------------------------------------------------------------------------
// Fused deformable conv v19: v13's exact data path with the LDS time-share
// ELIMINATED. Dynamic LDS = 108 segs (wob 0..35, wkb 36..107) = 110592 B,
// staged ONCE; then ONE barrier; then all 8 waves free-run (offset conv ->
// phase1 -> shuffles -> 9-tap loop) with ZERO further synchronization.
// Theory: 7 structural variants all hit 46-48us because 5-7 barriers
// phase-lock waves into stalling simultaneously (~25us dead time). Read-only
// LDS after bar0 removes every one of them. 256 persistent blocks (1/CU,
// all resident) x 2 rows each; weights stay hot for row 2.
// ---------------------------------------------------------------------------

#define BFBUILD(C, kc, BF, W0, W1, W2, W3)                                   \
    do {                                                                     \
        const unsigned* t0 = (const unsigned*)&(C)[(kc) * 4 + 0];            \
        const unsigned* t1 = (const unsigned*)&(C)[(kc) * 4 + 1];            \
        const unsigned* b0 = (const unsigned*)&(C)[(kc) * 4 + 2];            \
        const unsigned* b1 = (const unsigned*)&(C)[(kc) * 4 + 3];            \
        _Pragma("unroll")                                                    \
        for (int jd = 0; jd < 4; ++jd) {                                     \
            f32x2 t0p = {__uint_as_float(t0[jd] << 16),                      \
                         __uint_as_float(t0[jd] & 0xFFFF0000u)};             \
            f32x2 t1p = {__uint_as_float(t1[jd] << 16),                      \
                         __uint_as_float(t1[jd] & 0xFFFF0000u)};             \
            f32x2 b0p = {__uint_as_float(b0[jd] << 16),                      \
                         __uint_as_float(b0[jd] & 0xFFFF0000u)};             \
            f32x2 b1p = {__uint_as_float(b1[jd] << 16),                      \
                         __uint_as_float(b1[jd] & 0xFFFF0000u)};             \
            f32x2 vv = t0p * (W0) + t1p * (W1) + b0p * (W2) + b1p * (W3);    \
            unsigned pk;                                                     \
            asm("v_cvt_pk_bf16_f32 %0, %1, %2"                               \
                : "=v"(pk) : "v"(vv.x), "v"(vv.y));                          \
            (BF).u[jd] = pk;                                                 \
        }                                                                    \
    } while (0)

// SOFF = 36 (wkb lives at segs 36..107, no overwrites ever)
#define TAP(k)                                                               \
    do {                                                                     \
        const uint4* C = R[(k) & 1];                                         \
        union { unsigned u; __half2 hv; } c01, c23;                          \
        c01.u = pw01[(k)]; c23.u = pw23[(k)];                                \
        float W0 = __low2float(c01.hv), W1 = __high2float(c01.hv);           \
        float W2 = __low2float(c23.hv), W3 = __high2float(c23.hv);           \
        union { bf16x8 v; unsigned u[4]; } bfa, bfb;                         \
        BFBUILD(C, 0, bfa, W0, W1, W2, W3);                                  \
        BFBUILD(C, 1, bfb, W0, W1, W2, W3);                                  \
        _Pragma("unroll")                                                    \
        for (int ot = 0; ot < 4; ++ot) {                                     \
            bf16x8 af0 = s_w[(((k) * 2 + 0) * 4 + ot + 36) * 64 + lane];     \
            acc[ot] = __builtin_amdgcn_mfma_f32_16x16x32_bf16(               \
                af0, bfa.v, acc[ot], 0, 0, 0);                               \
            bf16x8 af1 = s_w[(((k) * 2 + 1) * 4 + ot + 36) * 64 + lane];     \
            acc[ot] = __builtin_amdgcn_mfma_f32_16x16x32_bf16(               \
                af1, bfb.v, acc[ot], 0, 0, 0);                               \
        }                                                                    \
    } while (0)

#define FETCH(kk, st)                                                \
    do {                                                             \
        unsigned ad_ = ad[kk];                                       \
        unsigned xc_ = ad_ >> 16;                                    \
        unsigned at_ = (((ad_ & 255u) << 7) + xc_) << 6;             \
        unsigned ab_ = ((((ad_ >> 8) & 255u) << 7) + xc_) << 6;      \
        R[st][0] = *(const uint4*)(xtb + at_ + co0);                 \
        R[st][1] = *(const uint4*)(xtb + at_ + 64 + co0);            \
        R[st][2] = *(const uint4*)(xtb + ab_ + co0);                 \
        R[st][3] = *(const uint4*)(xtb + ab_ + 64 + co0);            \
        R[st][4] = *(const uint4*)(xtb + at_ + co1);                 \
        R[st][5] = *(const uint4*)(xtb + at_ + 64 + co1);            \
        R[st][6] = *(const uint4*)(xtb + ab_ + co1);                 \
        R[st][7] = *(const uint4*)(xtb + ab_ + 64 + co1);            \
    } while (0)

__global__ __launch_bounds__(512, 2) void fused_deform_v19(
        const unsigned short* __restrict__ xt,
        const unsigned short* __restrict__ wob_sw,
        const unsigned short* __restrict__ wkb_sw,
        const float* __restrict__ b_off, float* __restrict__ out) {
    extern __shared__ bf16x8 s_w[];         // 108 segs = 110592 B dynamic

    int gid  = blockIdx.x;                  // 256 persistent blocks
    int tid  = threadIdx.x;
    int lane = tid & 63;
    int wave = __builtin_amdgcn_readfirstlane(tid >> 6);   // 0..7
    int l15  = lane & 15;
    int quad = lane >> 4;

    // ---- stage wob (segs 0..35) + wkb (segs 36..107) ONCE via DMA ----
    #pragma unroll
    for (int i = 0; i < 14; ++i) {
        int seg = i * 8 + wave;
        if (seg < 108) {
            const uint4* src = (seg < 36)
                ? (const uint4*)wob_sw + (size_t)seg * 64 + lane
                : (const uint4*)wkb_sw + (size_t)(seg - 36) * 64 + lane;
            dma16(src, (char*)s_w + (size_t)seg * 1024);
        }
    }

    bool first = true;
    #pragma unroll 1
    for (int row = 0; row < 2; ++row) {
        int gv   = gid + row * 256;         // virtual row id (v13 mapping)
        int xcd  = gv & 7;
        int j    = gv >> 3;
        int hh   = j & 15;
        int b    = j >> 4;
        int h    = xcd * 16 + hh;
        int p    = wave * 16 + l15;

        // ---- prefetch this row's 18 offset-tap fragments ----
        uint4 L[9][2];
        unsigned msk[9];
        const unsigned short* xtb = xt + (size_t)b * HW * 64;
        #pragma unroll
        for (int t9 = 0; t9 < 9; ++t9) {
            int ty = t9 / 3, tx = t9 % 3;
            int y  = h - 1 + ty;
            int xg = p - 1 + tx;
            bool v = (y >= 0) && (y < Hn) && (xg >= 0) && (xg < Wn);
            msk[t9] = v ? 0xFFFFFFFFu : 0u;
            int yc = min(max(y, 0), Hn - 1);
            int xc = min(max(xg, 0), Wn - 1);
            size_t base = ((size_t)yc * Wn + xc) * 64;
            L[t9][0] = *(const uint4*)(xtb + base + quad * 8);
            L[t9][1] = *(const uint4*)(xtb + base + 32 + quad * 8);
        }
        if (first) {                        // the ONLY barrier in the kernel
            __syncthreads();                // drains DMA vmcnt + joins waves
            first = false;
        }

        // ---- offset conv: 36 MFMA (reads segs 0..35, read-only) ----
        f32x4 oa0 = (f32x4){0.f, 0.f, 0.f, 0.f};
        f32x4 oa1 = (f32x4){0.f, 0.f, 0.f, 0.f};
        #pragma unroll
        for (int t9 = 0; t9 < 9; ++t9) {
            unsigned m = msk[t9];
            #pragma unroll
            for (int kc = 0; kc < 2; ++kc) {
                union { bf16x8 v; uint4 u; } bf;
                bf.u = L[t9][kc];
                bf.u.x &= m; bf.u.y &= m; bf.u.z &= m; bf.u.w &= m;
                bf16x8 a0 = s_w[((t9 * 2 + kc) * 2 + 0) * 64 + lane];
                bf16x8 a1 = s_w[((t9 * 2 + kc) * 2 + 1) * 64 + lane];
                oa0 = __builtin_amdgcn_mfma_f32_16x16x32_bf16(a0, bf.v, oa0, 0, 0, 0);
                oa1 = __builtin_amdgcn_mfma_f32_16x16x32_bf16(a1, bf.v, oa1, 0, 0, 0);
            }
        }

        // ---- phase-1 (lane (l15,q): taps 2q,2q+1; quad0: tap 8) ----
        unsigned my_ad[3]  = {0, 0, 0};
        unsigned my_w01[3] = {0, 0, 0};
        unsigned my_w23[3] = {0, 0, 0};
        auto phase1 = [&](int k, float dy, float dx, int slot) {
            float py  = (float)(h - 1 + k / 3) + dy;
            float pxf = (float)(p - 1 + k % 3) + dx;
            float y0f = floorf(py), x0f = floorf(pxf);
            float fy = py - y0f, fx = pxf - x0f;
            int y0 = (int)y0f, x0 = (int)x0f;
            bool vy0 = (y0 >= 0) & (y0 < Hn);
            bool vy1 = (y0 + 1 >= 0) & (y0 + 1 < Hn);
            bool vx0 = (x0 >= 0) & (x0 < Wn);
            bool vx1 = (x0 + 1 >= 0) & (x0 + 1 < Wn);
            float wy0 = vy0 ? 1.f - fy : 0.f;
            float wy1 = vy1 ? fy : 0.f;
            float wx0 = vx0 ? 1.f - fx : 0.f;
            float wx1 = vx1 ? fx : 0.f;
            int xc = min(max(x0, 0), Wn - 2);
            bool sel0 = (min(max(x0, 0), Wn - 1) != xc);
            bool sel1 = ((min(max(x0 + 1, 0), Wn - 1) - xc) == 1);
            float Wa = (sel0 ? 0.f : wx0) + (sel1 ? 0.f : wx1);
            float Wb = (sel0 ? wx0 : 0.f) + (sel1 ? wx1 : 0.f);
            int yc0 = min(max(y0, 0), Hn - 1), yc1 = min(max(y0 + 1, 0), Hn - 1);
            union { __half2 hv; unsigned u; } c01, c23;
            c01.hv = __floats2half2_rn(wy0 * Wa, wy0 * Wb);
            c23.hv = __floats2half2_rn(wy1 * Wa, wy1 * Wb);
            my_ad[slot]  = (unsigned)yc0 | ((unsigned)yc1 << 8) | ((unsigned)xc << 16);
            my_w01[slot] = c01.u;
            my_w23[slot] = c23.u;
        };
        int kb = quad * 2;
        phase1(kb,     oa0[0] + b_off[4 * quad],     oa0[1] + b_off[4 * quad + 1], 0);
        phase1(kb + 1, oa0[2] + b_off[4 * quad + 2], oa0[3] + b_off[4 * quad + 3], 1);
        if (quad == 0)
            phase1(8, oa1[0] + b_off[16], oa1[1] + b_off[17], 2);

        // ---- redistribute via shuffles (wave-local, no barrier) ----
        unsigned ad[KKc], pw01[KKc], pw23[KKc];
        #pragma unroll
        for (int k = 0; k < KKc; ++k) {
            int src  = (k < 8) ? ((k >> 1) * 16 + l15) : l15;
            int slot = (k < 8) ? (k & 1) : 2;
            ad[k]   = (unsigned)__shfl((int)my_ad[slot],  src, 64);
            pw01[k] = (unsigned)__shfl((int)my_w01[slot], src, 64);
            pw23[k] = (unsigned)__shfl((int)my_w23[slot], src, 64);
        }

        f32x4 acc[4];
        #pragma unroll
        for (int ot = 0; ot < 4; ++ot) acc[ot] = (f32x4){0.f, 0.f, 0.f, 0.f};

        uint4 R[2][8];
        int co0 = quad * 8, co1 = 32 + quad * 8;

        // ---- barrier-free 9-tap pipelined loop (wkb resident, segs 36+) ----
        FETCH(0, 0);
        FETCH(1, 1); TAP(0);
        FETCH(2, 0); TAP(1);
        FETCH(3, 1); TAP(2);
        FETCH(4, 0); TAP(3);
        FETCH(5, 1); TAP(4);
        FETCH(6, 0); TAP(5);
        FETCH(7, 1); TAP(6);
        FETCH(8, 0); TAP(7);
        TAP(8);

        #pragma unroll
        for (int ot = 0; ot < 4; ++ot)
            #pragma unroll
            for (int rr = 0; rr < 4; ++rr) {
                int o = ot * 16 + quad * 4 + rr;
                out[(((size_t)b * COUTc + o) * Hn + h) * Wn + p] = acc[ot][rr];
            }
    }
}

// ---------------------------------------------------------------------------
extern "C" void kernel_launch(void* const* d_in, const int* in_sizes, int n_in,
                              void* d_out, int out_size, void* d_ws, size_t ws_size,
                              hipStream_t stream) {
    const float* x     = (const float*)d_in[0];
    const float* w_off = (const float*)d_in[1];
    const float* b_off = (const float*)d_in[2];
    const float* w_def = (const float*)d_in[3];
    float* out = (float*)d_out;

    char* ws = (char*)d_ws;
    unsigned short* xt = (unsigned short*)ws;                 // 8.39 MB
    ws += (size_t)Bn * HW * CINc * sizeof(unsigned short);
    unsigned short* wkb_sw = (unsigned short*)ws;             // 73728 B
    ws += 36864 * sizeof(unsigned short);
    unsigned short* wob_sw = (unsigned short*)ws;             // 36864 B

    static bool attr_set = false;
    if (!attr_set) {
        (void)hipFuncSetAttribute((const void*)fused_deform_v19,
                                  hipFuncAttributeMaxDynamicSharedMemorySize,
                                  110592);
        attr_set = true;
    }

    prep_all<<<1024 + 216, 256, 0, stream>>>(x, xt, w_off, w_def, wkb_sw, wob_sw);
    fused_deform_v19<<<256, 512, 110592, stream>>>(xt, wob_sw, wkb_sw, b_off, out);
}

// Round 13
// 97.115 us; speedup vs baseline: 1.9084x; 1.1991x over previous
//
#include <hip/hip_runtime.h>
#include <hip/hip_fp16.h>

#define Bn   4
#define CINc 64
#define COUTc 64
#define Hn   128
#define Wn   128
#define HW   (Hn * Wn)
#define KKc  9
#define NOFF 18

typedef short bf16x8 __attribute__((ext_vector_type(8)));
typedef float f32x4  __attribute__((ext_vector_type(4)));
typedef float f32x2  __attribute__((ext_vector_type(2)));

__device__ inline unsigned short f2bf(float f) {   // RNE fp32 -> bf16
    unsigned int u = __float_as_uint(f);
    return (unsigned short)((u + 0x7fffu + ((u >> 16) & 1u)) >> 16);
}

__device__ inline void dma16(const void* g, void* l) {
#if __has_builtin(__builtin_amdgcn_global_load_lds)
    __builtin_amdgcn_global_load_lds(
        (__attribute__((address_space(1))) void*)(g),
        (__attribute__((address_space(3))) void*)(l), 16, 0, 0);
#else
    *(uint4*)l = *(const uint4*)g;
#endif
}

// ---------------------------------------------------------------------------
// prep_all (v18: vectorized transpose loads) — unchanged.
// ---------------------------------------------------------------------------
__global__ __launch_bounds__(256) void prep_all(
        const float* __restrict__ x, unsigned short* __restrict__ xt,
        const float* __restrict__ w_off, const float* __restrict__ w_def,
        unsigned short* __restrict__ wkb_sw, unsigned short* __restrict__ wob_sw) {
    int gb = blockIdx.x;
    int t  = threadIdx.x;
    if (gb < 1024) {
        __shared__ float s[64][65];
        int half = gb & 1;
        int h    = (gb >> 1) & 127;
        int b    = gb >> 8;
        int w0   = half * 64;

        const float* xb = x + (size_t)b * CINc * HW + (size_t)h * Wn + w0;
        int c0 = t >> 4, wq = (t & 15) * 4;
        #pragma unroll
        for (int i = 0; i < 4; ++i) {
            int c = c0 + i * 16;
            float4 v = *(const float4*)(xb + (size_t)c * HW + wq);
            s[c][wq]     = v.x;
            s[c][wq + 1] = v.y;
            s[c][wq + 2] = v.z;
            s[c][wq + 3] = v.w;
        }
        __syncthreads();

        int cpair = t & 31, pxg = t >> 5;
        unsigned* xtp = (unsigned*)xt;
        #pragma unroll
        for (int i = 0; i < 8; ++i) {
            int px = pxg * 8 + i;
            float v0 = s[cpair * 2][px], v1 = s[cpair * 2 + 1][px];
            unsigned d = (unsigned)f2bf(v0) | ((unsigned)f2bf(v1) << 16);
            xtp[(((size_t)(b * Hn + h) * Wn) + w0 + px) * 32 + cpair] = d;
        }
        return;
    }
    int idx = (gb - 1024) * 256 + t;
    if (idx < 36864) {
        int j = idx & 7, l = (idx >> 3) & 63, s = idx >> 9;
        int k = s >> 3, kc = (s >> 2) & 1, ot = s & 3;
        int l15 = l & 15, quad = l >> 4;
        int o = ot * 16 + l15, c = kc * 32 + quad * 8 + j;
        wkb_sw[idx] = f2bf(w_def[((size_t)o * 64 + c) * 9 + k]);
    }
    int i2 = idx - 36864;
    if (i2 >= 0 && i2 < 18432) {
        int j = i2 & 7, l = (i2 >> 3) & 63, s = i2 >> 9;
        int tt = s >> 2, kc = (s >> 1) & 1, mt = s & 1;
        int l15 = l & 15, quad = l >> 4;
        int m = mt * 16 + l15, c = kc * 32 + quad * 8 + j;
        unsigned short v = 0;
        if (m < NOFF) v = f2bf(w_off[((size_t)m * 64 + c) * 9 + tt]);
        wob_sw[i2] = v;
    }
}

// ---------------------------------------------------------------------------
// Fused deformable conv v20: gathers moved from scattered GLOBAL loads to
// swizzled LDS reads. Theory: per-CU row time (23us) is TA/L1 address
// processing of ~16-line-scattered loads, with ~12x line re-touch (offsets
// are tiny). LDS layout:
//   [0, 81920):   x-window, 5 rows y=clamp(h-2+r), swizzled: logical chunk j
//                 of pixel x lives at (r*128+x)*128 + (j^(x&7))*16.
//   [81920, +73728): wob (36.9KB, offset phase) then wkb (73.7KB, main loop).
// Total 152KB, 1 block/CU, 512 blocks. Staging uses pre-swizzled per-lane
// GLOBAL source + linear LDS dest (global_load_lds rule). If any tap's y
// leaves the window (offsets >=1; ~never), the whole block uses the exact
// v13 global path (wave-uniform branch) -> correct for arbitrary offsets.
// ---------------------------------------------------------------------------

#define BFBUILD(C, kc, BF, W0, W1, W2, W3)                                   \
    do {                                                                     \
        const unsigned* t0 = (const unsigned*)&(C)[(kc) * 4 + 0];            \
        const unsigned* t1 = (const unsigned*)&(C)[(kc) * 4 + 1];            \
        const unsigned* b0 = (const unsigned*)&(C)[(kc) * 4 + 2];            \
        const unsigned* b1 = (const unsigned*)&(C)[(kc) * 4 + 3];            \
        _Pragma("unroll")                                                    \
        for (int jd = 0; jd < 4; ++jd) {                                     \
            f32x2 t0p = {__uint_as_float(t0[jd] << 16),                      \
                         __uint_as_float(t0[jd] & 0xFFFF0000u)};             \
            f32x2 t1p = {__uint_as_float(t1[jd] << 16),                      \
                         __uint_as_float(t1[jd] & 0xFFFF0000u)};             \
            f32x2 b0p = {__uint_as_float(b0[jd] << 16),                      \
                         __uint_as_float(b0[jd] & 0xFFFF0000u)};             \
            f32x2 b1p = {__uint_as_float(b1[jd] << 16),                      \
                         __uint_as_float(b1[jd] & 0xFFFF0000u)};             \
            f32x2 vv = t0p * (W0) + t1p * (W1) + b0p * (W2) + b1p * (W3);    \
            unsigned pk;                                                     \
            asm("v_cvt_pk_bf16_f32 %0, %1, %2"                               \
                : "=v"(pk) : "v"(vv.x), "v"(vv.y));                          \
            (BF).u[jd] = pk;                                                 \
        }                                                                    \
    } while (0)

#define TAP(k)                                                               \
    do {                                                                     \
        const uint4* C = R[(k) & 1];                                         \
        union { unsigned u; __half2 hv; } c01, c23;                          \
        c01.u = pw01[(k)]; c23.u = pw23[(k)];                                \
        float W0 = __low2float(c01.hv), W1 = __high2float(c01.hv);           \
        float W2 = __low2float(c23.hv), W3 = __high2float(c23.hv);           \
        union { bf16x8 v; unsigned u[4]; } bfa, bfb;                         \
        BFBUILD(C, 0, bfa, W0, W1, W2, W3);                                  \
        BFBUILD(C, 1, bfb, W0, W1, W2, W3);                                  \
        _Pragma("unroll")                                                    \
        for (int ot = 0; ot < 4; ++ot) {                                     \
            bf16x8 af0 = s_wv[(((k) * 2 + 0) * 4 + ot) * 64 + lane];         \
            acc[ot] = __builtin_amdgcn_mfma_f32_16x16x32_bf16(               \
                af0, bfa.v, acc[ot], 0, 0, 0);                               \
            bf16x8 af1 = s_wv[(((k) * 2 + 1) * 4 + ot) * 64 + lane];         \
            acc[ot] = __builtin_amdgcn_mfma_f32_16x16x32_bf16(               \
                af1, bfb.v, acc[ot], 0, 0, 0);                               \
        }                                                                    \
    } while (0)

// global-path fetch (v13 verbatim) — fallback when window is exceeded
#define FETCH_G(kk, st)                                              \
    do {                                                             \
        unsigned ad_ = ad[kk];                                       \
        unsigned xc_ = ad_ >> 16;                                    \
        unsigned at_ = (((ad_ & 255u) << 7) + xc_) << 6;             \
        unsigned ab_ = ((((ad_ >> 8) & 255u) << 7) + xc_) << 6;      \
        R[st][0] = *(const uint4*)(xtb + at_ + co0);                 \
        R[st][1] = *(const uint4*)(xtb + at_ + 64 + co0);            \
        R[st][2] = *(const uint4*)(xtb + ab_ + co0);                 \
        R[st][3] = *(const uint4*)(xtb + ab_ + 64 + co0);            \
        R[st][4] = *(const uint4*)(xtb + at_ + co1);                 \
        R[st][5] = *(const uint4*)(xtb + at_ + 64 + co1);            \
        R[st][6] = *(const uint4*)(xtb + ab_ + co1);                 \
        R[st][7] = *(const uint4*)(xtb + ab_ + 64 + co1);            \
    } while (0)

// LDS-window fetch: same bytes, swizzled window reads
#define FETCH_L(kk, st)                                              \
    do {                                                             \
        unsigned ad_ = ad[kk];                                       \
        int xc_ = (int)(ad_ >> 16);                                  \
        int r0_ = (int)(ad_ & 255u) - h + 2;                         \
        int r1_ = (int)((ad_ >> 8) & 255u) - h + 2;                  \
        int b00 = (r0_ * 128 + xc_) * 128;                           \
        int b10 = (r1_ * 128 + xc_) * 128;                           \
        int j0  = (quad ^ (xc_ & 7)) << 4;                           \
        int j1  = (quad ^ ((xc_ + 1) & 7)) << 4;                     \
        int j0b = ((4 + quad) ^ (xc_ & 7)) << 4;                     \
        int j1b = ((4 + quad) ^ ((xc_ + 1) & 7)) << 4;               \
        R[st][0] = *(const uint4*)(s_mem + b00 + j0);                \
        R[st][1] = *(const uint4*)(s_mem + b00 + 128 + j1);          \
        R[st][2] = *(const uint4*)(s_mem + b10 + j0);                \
        R[st][3] = *(const uint4*)(s_mem + b10 + 128 + j1);          \
        R[st][4] = *(const uint4*)(s_mem + b00 + j0b);               \
        R[st][5] = *(const uint4*)(s_mem + b00 + 128 + j1b);         \
        R[st][6] = *(const uint4*)(s_mem + b10 + j0b);               \
        R[st][7] = *(const uint4*)(s_mem + b10 + 128 + j1b);         \
    } while (0)

__global__ __launch_bounds__(512, 2) void fused_deform_v20(
        const unsigned short* __restrict__ xt,
        const unsigned short* __restrict__ wob_sw,
        const unsigned short* __restrict__ wkb_sw,
        const float* __restrict__ b_off, float* __restrict__ out) {
    extern __shared__ char s_mem[];                 // 155648 B dynamic
    bf16x8* s_wv = (bf16x8*)(s_mem + 81920);        // wob/wkb region

    int gid  = blockIdx.x;                  // 512
    int xcd  = gid & 7;
    int j    = gid >> 3;
    int hh   = j & 15;
    int b    = j >> 4;
    int h    = xcd * 16 + hh;
    int tid  = threadIdx.x;
    int lane = tid & 63;
    int wave = __builtin_amdgcn_readfirstlane(tid >> 6);   // 0..7
    int l15  = lane & 15;
    int quad = lane >> 4;
    int p    = wave * 16 + l15;

    const unsigned short* xtb = xt + (size_t)b * HW * 64;

    // ---- stage x-window (5 rows, swizzled content, linear dest) ----
    int xl = lane >> 3;                     // pixel within 8-px group
    int sl = lane & 7;                      // dest 16B slot
    #pragma unroll
    for (int i = 0; i < 10; ++i) {
        int slot = i * 8 + wave;            // 0..79 (r,g) pairs
        int r  = slot >> 4;                 // 0..4
        int g  = slot & 15;                 // 0..15
        int y  = min(max(h - 2 + r, 0), Hn - 1);
        int xx = g * 8 + xl;
        int jj = sl ^ (xx & 7);             // pre-swizzled source chunk
        dma16(xtb + ((size_t)y * Wn + xx) * 64 + jj * 8,
              s_mem + (size_t)r * 16384 + (size_t)g * 1024);
    }
    // ---- stage wob into weight region ----
    #pragma unroll
    for (int i = 0; i < 5; ++i) {
        int seg = i * 8 + wave;
        if (seg < 36)
            dma16((const uint4*)wob_sw + seg * 64 + lane,
                  s_mem + 81920 + (size_t)seg * 1024);
    }
    __syncthreads();                        // bar0: x-window + wob staged

    // ---- offset conv: 36 MFMA, B-operand from LDS window ----
    f32x4 oa0 = (f32x4){0.f, 0.f, 0.f, 0.f};
    f32x4 oa1 = (f32x4){0.f, 0.f, 0.f, 0.f};
    #pragma unroll
    for (int t9 = 0; t9 < 9; ++t9) {
        int ty = t9 / 3, tx = t9 % 3;
        int y  = h - 1 + ty;
        int xg = p - 1 + tx;
        bool v = (y >= 0) && (y < Hn) && (xg >= 0) && (xg < Wn);
        unsigned m = v ? 0xFFFFFFFFu : 0u;
        int yc = min(max(y, 0), Hn - 1);
        int xc = min(max(xg, 0), Wn - 1);
        int r  = yc - h + 2;                // always in [0,4]
        int base = (r * 128 + xc) * 128;
        uint4 L0 = *(const uint4*)(s_mem + base + ((quad ^ (xc & 7)) << 4));
        uint4 L1 = *(const uint4*)(s_mem + base + (((4 + quad) ^ (xc & 7)) << 4));
        #pragma unroll
        for (int kc = 0; kc < 2; ++kc) {
            union { bf16x8 v; uint4 u; } bf;
            bf.u = kc ? L1 : L0;
            bf.u.x &= m; bf.u.y &= m; bf.u.z &= m; bf.u.w &= m;
            bf16x8 a0 = s_wv[((t9 * 2 + kc) * 2 + 0) * 64 + lane];
            bf16x8 a1 = s_wv[((t9 * 2 + kc) * 2 + 1) * 64 + lane];
            oa0 = __builtin_amdgcn_mfma_f32_16x16x32_bf16(a0, bf.v, oa0, 0, 0, 0);
            oa1 = __builtin_amdgcn_mfma_f32_16x16x32_bf16(a1, bf.v, oa1, 0, 0, 0);
        }
    }

    // ---- phase-1 (v13 verbatim) ----
    unsigned my_ad[3]  = {0, 0, 0};
    unsigned my_w01[3] = {0, 0, 0};
    unsigned my_w23[3] = {0, 0, 0};
    auto phase1 = [&](int k, float dy, float dx, int slot) {
        float py  = (float)(h - 1 + k / 3) + dy;
        float pxf = (float)(p - 1 + k % 3) + dx;
        float y0f = floorf(py), x0f = floorf(pxf);
        float fy = py - y0f, fx = pxf - x0f;
        int y0 = (int)y0f, x0 = (int)x0f;
        bool vy0 = (y0 >= 0) & (y0 < Hn);
        bool vy1 = (y0 + 1 >= 0) & (y0 + 1 < Hn);
        bool vx0 = (x0 >= 0) & (x0 < Wn);
        bool vx1 = (x0 + 1 >= 0) & (x0 + 1 < Wn);
        float wy0 = vy0 ? 1.f - fy : 0.f;
        float wy1 = vy1 ? fy : 0.f;
        float wx0 = vx0 ? 1.f - fx : 0.f;
        float wx1 = vx1 ? fx : 0.f;
        int xc = min(max(x0, 0), Wn - 2);
        bool sel0 = (min(max(x0, 0), Wn - 1) != xc);
        bool sel1 = ((min(max(x0 + 1, 0), Wn - 1) - xc) == 1);
        float Wa = (sel0 ? 0.f : wx0) + (sel1 ? 0.f : wx1);
        float Wb = (sel0 ? wx0 : 0.f) + (sel1 ? wx1 : 0.f);
        int yc0 = min(max(y0, 0), Hn - 1), yc1 = min(max(y0 + 1, 0), Hn - 1);
        union { __half2 hv; unsigned u; } c01, c23;
        c01.hv = __floats2half2_rn(wy0 * Wa, wy0 * Wb);
        c23.hv = __floats2half2_rn(wy1 * Wa, wy1 * Wb);
        my_ad[slot]  = (unsigned)yc0 | ((unsigned)yc1 << 8) | ((unsigned)xc << 16);
        my_w01[slot] = c01.u;
        my_w23[slot] = c23.u;
    };
    int kb = quad * 2;
    phase1(kb,     oa0[0] + b_off[4 * quad],     oa0[1] + b_off[4 * quad + 1], 0);
    phase1(kb + 1, oa0[2] + b_off[4 * quad + 2], oa0[3] + b_off[4 * quad + 3], 1);
    if (quad == 0)
        phase1(8, oa1[0] + b_off[16], oa1[1] + b_off[17], 2);
    __syncthreads();                        // bar1: wob LDS reads done

    // ---- stage wkb (72 segs) over wob region; shuffles cover flight ----
    #pragma unroll
    for (int i = 0; i < 9; ++i) {
        int seg = i * 8 + wave;
        dma16((const uint4*)wkb_sw + (size_t)seg * 64 + lane,
              s_mem + 81920 + (size_t)seg * 1024);
    }

    unsigned ad[KKc], pw01[KKc], pw23[KKc];
    #pragma unroll
    for (int k = 0; k < KKc; ++k) {
        int src  = (k < 8) ? ((k >> 1) * 16 + l15) : l15;
        int slot = (k < 8) ? (k & 1) : 2;
        ad[k]   = (unsigned)__shfl((int)my_ad[slot],  src, 64);
        pw01[k] = (unsigned)__shfl((int)my_w01[slot], src, 64);
        pw23[k] = (unsigned)__shfl((int)my_w23[slot], src, 64);
    }
    __syncthreads();                        // bar2: wkb visible

    // ---- window test: all 9 taps' y-rows inside [h-2, h+2]? ----
    bool oow = false;
    #pragma unroll
    for (int k = 0; k < KKc; ++k) {
        int r0 = (int)(ad[k] & 255u) - h + 2;
        int r1 = (int)((ad[k] >> 8) & 255u) - h + 2;
        oow |= ((unsigned)r0 > 4u) | ((unsigned)r1 > 4u);
    }
    bool use_global = __any(oow);           // wave-uniform

    f32x4 acc[4];
    #pragma unroll
    for (int ot = 0; ot < 4; ++ot) acc[ot] = (f32x4){0.f, 0.f, 0.f, 0.f};

    uint4 R[2][8];
    int co0 = quad * 8, co1 = 32 + quad * 8;

    if (__builtin_expect(use_global, 0)) {
        // ---- fallback: exact v13 global gather loop ----
        FETCH_G(0, 0);
        FETCH_G(1, 1); TAP(0);
        FETCH_G(2, 0); TAP(1);
        FETCH_G(3, 1); TAP(2);
        FETCH_G(4, 0); TAP(3);
        FETCH_G(5, 1); TAP(4);
        FETCH_G(6, 0); TAP(5);
        FETCH_G(7, 1); TAP(6);
        FETCH_G(8, 0); TAP(7);
        TAP(8);
    } else {
        // ---- fast path: swizzled LDS window gathers ----
        FETCH_L(0, 0);
        FETCH_L(1, 1); TAP(0);
        FETCH_L(2, 0); TAP(1);
        FETCH_L(3, 1); TAP(2);
        FETCH_L(4, 0); TAP(3);
        FETCH_L(5, 1); TAP(4);
        FETCH_L(6, 0); TAP(5);
        FETCH_L(7, 1); TAP(6);
        FETCH_L(8, 0); TAP(7);
        TAP(8);
    }

    #pragma unroll
    for (int ot = 0; ot < 4; ++ot)
        #pragma unroll
        for (int rr = 0; rr < 4; ++rr) {
            int o = ot * 16 + quad * 4 + rr;
            out[(((size_t)b * COUTc + o) * Hn + h) * Wn + p] = acc[ot][rr];
        }
}

// ---------------------------------------------------------------------------
extern "C" void kernel_launch(void* const* d_in, const int* in_sizes, int n_in,
                              void* d_out, int out_size, void* d_ws, size_t ws_size,
                              hipStream_t stream) {
    const float* x     = (const float*)d_in[0];
    const float* w_off = (const float*)d_in[1];
    const float* b_off = (const float*)d_in[2];
    const float* w_def = (const float*)d_in[3];
    float* out = (float*)d_out;

    char* ws = (char*)d_ws;
    unsigned short* xt = (unsigned short*)ws;                 // 8.39 MB
    ws += (size_t)Bn * HW * CINc * sizeof(unsigned short);
    unsigned short* wkb_sw = (unsigned short*)ws;             // 73728 B
    ws += 36864 * sizeof(unsigned short);
    unsigned short* wob_sw = (unsigned short*)ws;             // 36864 B

    static bool attr_set = false;
    if (!attr_set) {
        (void)hipFuncSetAttribute((const void*)fused_deform_v20,
                                  hipFuncAttributeMaxDynamicSharedMemorySize,
                                  155648);
        attr_set = true;
    }

    prep_all<<<1024 + 216, 256, 0, stream>>>(x, xt, w_off, w_def, wkb_sw, wob_sw);
    fused_deform_v20<<<Bn * Hn, 512, 155648, stream>>>(xt, wob_sw, wkb_sw, b_off, out);
}